// Round 10
// baseline (1825.995 us; speedup 1.0000x reference)
//
#include <hip/hip_runtime.h>

typedef __bf16 bf16_t;
typedef __bf16 bf16x8 __attribute__((ext_vector_type(8)));
typedef _Float16 f16x4 __attribute__((ext_vector_type(4)));
typedef unsigned short u16x8 __attribute__((ext_vector_type(8)));
typedef unsigned short u16x4 __attribute__((ext_vector_type(4)));
typedef float f32x4 __attribute__((ext_vector_type(4)));

#define MT 64
#define NTHR 512
#define TPB 32                              // tiles per persistent block
#define NPBLK (1048576 / (MT * TPB))        // 512 blocks = 2 per CU

// ---------------- fragment-native LDS layout ----------------------------------
// value(point p, neuron n): byte (pg*NK + (n>>5))*1024 + ((n>>3)&3)*256 + (p&15)*16 + (n&7)*2
// B-fragment (pgroup, kstep) = contiguous 1KB at (pg*NK + ks)*1024 + lane*16.
__device__ __forceinline__ int fragoff(int NK, int pg, int n, int p15) {
  return ((pg * NK + (n >> 5)) << 10) + (((n >> 3) & 3) << 8) + (p15 << 4) + ((n & 7) << 1);
}
__device__ __forceinline__ void st_frag1(char* buf, int NK, int pg, int n, int p15, float v) {
  *reinterpret_cast<unsigned short*>(buf + fragoff(NK, pg, n, p15)) =
      __builtin_bit_cast(unsigned short, (bf16_t)v);
}
__device__ __forceinline__ void st_frag4(char* buf, int NK, int pg, int n, int p15, float v0,
                                         float v1, float v2, float v3) {
  u16x4 pk;
  pk[0] = __builtin_bit_cast(unsigned short, (bf16_t)v0);
  pk[1] = __builtin_bit_cast(unsigned short, (bf16_t)v1);
  pk[2] = __builtin_bit_cast(unsigned short, (bf16_t)v2);
  pk[3] = __builtin_bit_cast(unsigned short, (bf16_t)v3);
  *reinterpret_cast<uint2*>(buf + fragoff(NK, pg, n, p15)) = __builtin_bit_cast(uint2, pk);
}

// ---------- prologue 1: transpose all 3 planes (32,H,W) fp32 -> (H*W,32) fp16 --
__global__ void KPlanes_tr3(const float* __restrict__ yx, const float* __restrict__ xt,
                            const float* __restrict__ yt, uint4* __restrict__ d0,
                            uint4* __restrict__ d1, uint4* __restrict__ d2) {
  const int HW0 = 518400, HW1 = 288000, HW2 = 162000;
  const int NB0 = 2025, NB1 = 1125;
  const int b = blockIdx.x;
  const float* src;
  uint4* dst;
  int HW, s;
  if (b < NB0) {
    src = yx; dst = d0; HW = HW0; s = b * 256 + threadIdx.x;
  } else if (b < NB0 + NB1) {
    src = xt; dst = d1; HW = HW1; s = (b - NB0) * 256 + threadIdx.x;
  } else {
    src = yt; dst = d2; HW = HW2; s = (b - NB0 - NB1) * 256 + threadIdx.x;
  }
  if (s >= HW) return;
#pragma unroll
  for (int g = 0; g < 4; ++g) {
    u16x8 v;
#pragma unroll
    for (int j = 0; j < 8; ++j) {
      const float w = src[(size_t)(g * 8 + j) * HW + s];
      v[j] = __builtin_bit_cast(unsigned short, (_Float16)w);
    }
    dst[(size_t)s * 4 + g] = __builtin_bit_cast(uint4, v);
  }
}

// ---------- prologue 2: pack ALL fp32 weights into bf16 MFMA fragments --------
__global__ void KPlanes_packall(const float* __restrict__ fw1, const float* __restrict__ fw2,
                                const float* __restrict__ w1, const float* __restrict__ w2,
                                const float* __restrict__ w3, const float* __restrict__ w4,
                                uint4* __restrict__ dst) {
  const int F = blockIdx.x * 4 + (threadIdx.x >> 6);
  const int lane = threadIdx.x & 63;
  if (F >= 340) return;
  const float* W;
  int N, K, KS, fbase;
  if (F < 4)        { W = fw1; N = 64;  K = 32;  KS = 1; fbase = 0; }
  else if (F < 12)  { W = fw2; N = 64;  K = 64;  KS = 2; fbase = 4; }
  else if (F < 76)  { W = w1;  N = 256; K = 119; KS = 4; fbase = 12; }
  else if (F < 204) { W = w2;  N = 256; K = 256; KS = 8; fbase = 76; }
  else if (F < 332) { W = w3;  N = 256; K = 256; KS = 8; fbase = 204; }
  else              { W = w4;  N = 3;   K = 256; KS = 8; fbase = 332; }
  const int f = F - fbase;
  const int g = f / KS, ks = f - g * KS;
  const int col = g * 16 + (lane & 15);
  u16x8 v;
#pragma unroll
  for (int j = 0; j < 8; ++j) {
    const int k = ks * 32 + (lane >> 4) * 8 + j;
    const float w = (k < K && col < N) ? W[(size_t)k * N + col] : 0.0f;
    v[j] = __builtin_bit_cast(unsigned short, (bf16_t)w);
  }
  dst[(size_t)F * 64 + lane] = __builtin_bit_cast(uint4, v);
}

// ---------- fp16 bilinear sample, 4 channels per thread -----------------------
struct Smp4 {
  uint2 c00, c01, c10, c11;
  float w00, w01, w10, w11;
};
__device__ __forceinline__ Smp4 sample_ld4(const uint2* __restrict__ plt, int Hd, int Wd, float u,
                                           float v, int q) {
  Smp4 s;
  float ix = fminf(fmaxf(u * (float)Wd - 0.5f, 0.f), (float)Wd - 1.f);
  float iy = fminf(fmaxf(v * (float)Hd - 0.5f, 0.f), (float)Hd - 1.f);
  float x0f = floorf(ix), y0f = floorf(iy);
  float wx = ix - x0f, wy = iy - y0f;
  int x0 = (int)x0f, y0 = (int)y0f;
  int x1 = min(x0 + 1, Wd - 1), y1 = min(y0 + 1, Hd - 1);
  s.w00 = (1.f - wx) * (1.f - wy);
  s.w01 = wx * (1.f - wy);
  s.w10 = (1.f - wx) * wy;
  s.w11 = wx * wy;
  const size_t r0 = (size_t)y0 * Wd, r1 = (size_t)y1 * Wd;
  s.c00 = plt[(r0 + x0) * 8 + q];
  s.c01 = plt[(r0 + x1) * 8 + q];
  s.c10 = plt[(r1 + x0) * 8 + q];
  s.c11 = plt[(r1 + x1) * 8 + q];
  return s;
}
__device__ __forceinline__ void smp_combine4(const Smp4& s, float* o) {
  const f16x4 a = __builtin_bit_cast(f16x4, s.c00);
  const f16x4 b = __builtin_bit_cast(f16x4, s.c01);
  const f16x4 c = __builtin_bit_cast(f16x4, s.c10);
  const f16x4 d = __builtin_bit_cast(f16x4, s.c11);
#pragma unroll
  for (int i = 0; i < 4; ++i)
    o[i] = (float)a[i] * s.w00 + (float)b[i] * s.w01 + (float)c[i] * s.w10 + (float)d[i] * s.w11;
}

// ---------- ping-pong MFMA layer on fragment-native LDS (unchanged from R7) ---
template <int KS, int NKOUT, int NT, int MTPW, bool RELU>
__device__ __forceinline__ void layer_fp(const char* in, char* outb, const uint4* __restrict__ Wf,
                                         const float* __restrict__ bg, int gbase, int moff,
                                         int lane) {
  const int l15 = lane & 15, lhi = lane >> 4;
  const char* rb = in + lane * 16 + moff * (KS << 10);
  f32x4 acc[MTPW][NT];
#pragma unroll
  for (int m = 0; m < MTPW; ++m)
#pragma unroll
    for (int t = 0; t < NT; ++t) acc[m][t] = f32x4{0.f, 0.f, 0.f, 0.f};
#pragma unroll
  for (int ks = 0; ks < KS; ++ks) {
    bf16x8 wa[NT];
#pragma unroll
    for (int t = 0; t < NT; ++t)
      wa[t] = __builtin_bit_cast(bf16x8, Wf[(size_t)((gbase + t) * KS + ks) * 64 + lane]);
#pragma unroll
    for (int m = 0; m < MTPW; ++m) {
      const uint4 u = *reinterpret_cast<const uint4*>(rb + ((m * KS + ks) << 10));
      const bf16x8 b = __builtin_bit_cast(bf16x8, u);
#pragma unroll
      for (int t = 0; t < NT; ++t)
        acc[m][t] = __builtin_amdgcn_mfma_f32_16x16x32_bf16(wa[t], b, acc[m][t], 0, 0, 0);
    }
  }
#pragma unroll
  for (int t = 0; t < NT; ++t) {
    const int ncol = (gbase + t) * 16 + lhi * 4;
    const float4 bb = *reinterpret_cast<const float4*>(&bg[ncol]);
#pragma unroll
    for (int m = 0; m < MTPW; ++m) {
      float v0 = acc[m][t][0] + bb.x, v1 = acc[m][t][1] + bb.y;
      float v2 = acc[m][t][2] + bb.z, v3 = acc[m][t][3] + bb.w;
      if (RELU) {
        v0 = fmaxf(v0, 0.f); v1 = fmaxf(v1, 0.f);
        v2 = fmaxf(v2, 0.f); v3 = fmaxf(v3, 0.f);
      }
      st_frag4(outb, NKOUT, moff + m, ncol, l15, v0, v1, v2, v3);
    }
  }
}

// ---------- persistent pipelined kernel: 512 blocks x 32 tiles ----------------
// Per iteration: combine tile i (gathers issued last iter -> latency hidden),
// pos-enc tile i, issue gathers i+1, prefetch coords i+2, then L1..L6 (= R7).
__global__ __launch_bounds__(NTHR, 4) void KPlanes_fusedP(
    const float* __restrict__ xyt, const uint2* __restrict__ yx_h, const uint2* __restrict__ xt_h,
    const uint2* __restrict__ yt_h, const uint4* __restrict__ wf1, const float* __restrict__ fb1,
    const uint4* __restrict__ wf2, const float* __restrict__ fb2, const uint4* __restrict__ wf3,
    const float* __restrict__ b1, const uint4* __restrict__ wf4, const float* __restrict__ b2,
    const uint4* __restrict__ wf5, const float* __restrict__ b3, const uint4* __restrict__ wf6,
    const float* __restrict__ b4, const int* __restrict__ fnum_p, float* __restrict__ out) {
  __shared__ char actS[32768];
  __shared__ char actB[32768];
  const int tid = threadIdx.x;
  const int lane = tid & 63;
  const int wid = tid >> 6;
  const float rfn = 1.0f / (float)(*fnum_p);
  const int p = tid >> 3, q = tid & 7;
  const int pg = p >> 4, p15 = p & 15;
  const int tbase = blockIdx.x * TPB;

  // ---- pipeline prologue: coords+gathers for tile 0, coords for tile 1
  float x, y, t, xn, yn, tn;
  {
    const int p0 = tbase * MT + p;
    x = xyt[p0 * 3 + 0];
    y = xyt[p0 * 3 + 1];
    t = xyt[p0 * 3 + 2] * rfn;
  }
  Smp4 sYX = sample_ld4(yx_h, 540, 960, y, x, q);
  Smp4 sXT = sample_ld4(xt_h, 960, 300, x, t, q);
  Smp4 sYT = sample_ld4(yt_h, 540, 300, y, t, q);
  {
    const int p1 = (tbase + 1) * MT + p;
    xn = xyt[p1 * 3 + 0];
    yn = xyt[p1 * 3 + 1];
    tn = xyt[p1 * 3 + 2] * rfn;
  }

#pragma unroll 1
  for (int it = 0; it < TPB; ++it) {
    // ---- combine tile it -> feat (vmcnt wait was covered by last iter's layers)
    {
      float a4[4], b4_[4], c4[4];
      smp_combine4(sYX, a4);
      smp_combine4(sXT, b4_);
      smp_combine4(sYT, c4);
      st_frag4(actS + 16384, 1, pg, q * 4, p15, a4[0] * b4_[0] * c4[0], a4[1] * b4_[1] * c4[1],
               a4[2] * b4_[2] * c4[2], a4[3] * b4_[3] * c4[3]);
    }
    // ---- pos-enc tile it from (x,y,t) into actS NK4 frags 2-3
    if (q == 4) {
      st_frag1(actS, 4, pg, 64, p15, y);
      float sj, cj;
      sincosf(y, &sj, &cj);
#pragma unroll
      for (int j = 0; j < 10; ++j) {
        st_frag1(actS, 4, pg, 66 + j * 4, p15, sj);
        st_frag1(actS, 4, pg, 68 + j * 4, p15, cj);
        const float ns = 2.f * sj * cj;
        cj = fmaf(-2.f * sj, sj, 1.f);
        sj = ns;
      }
    } else if (q == 5) {
      st_frag1(actS, 4, pg, 65, p15, x);
      float sj, cj;
      sincosf(x, &sj, &cj);
#pragma unroll
      for (int j = 0; j < 10; ++j) {
        st_frag1(actS, 4, pg, 67 + j * 4, p15, sj);
        st_frag1(actS, 4, pg, 69 + j * 4, p15, cj);
        const float ns = 2.f * sj * cj;
        cj = fmaf(-2.f * sj, sj, 1.f);
        sj = ns;
      }
    } else if (q == 6) {
      st_frag1(actS, 4, pg, 106, p15, t);
      float sj, cj;
      sincosf(t, &sj, &cj);
#pragma unroll
      for (int j = 0; j < 6; ++j) {
        st_frag1(actS, 4, pg, 107 + 2 * j, p15, sj);
        st_frag1(actS, 4, pg, 108 + 2 * j, p15, cj);
        const float ns = 2.f * sj * cj;
        cj = fmaf(-2.f * sj, sj, 1.f);
        sj = ns;
      }
    } else if (q == 7) {
      st_frag1(actS, 4, pg, 119, p15, 0.f);
      *reinterpret_cast<uint4*>(actS + fragoff(4, pg, 120, p15)) = uint4{0u, 0u, 0u, 0u};
    }
    // ---- issue gathers for tile it+1 (hidden under this iter's layer phase)
    if (it + 1 < TPB) {
      sYX = sample_ld4(yx_h, 540, 960, yn, xn, q);
      sXT = sample_ld4(xt_h, 960, 300, xn, tn, q);
      sYT = sample_ld4(yt_h, 540, 300, yn, tn, q);
    }
    // ---- prefetch coords for tile it+2 (clamped)
    float xn2, yn2, tn2;
    {
      const int it2 = (it + 2 < TPB) ? (it + 2) : (TPB - 1);
      const int p2 = (tbase + it2) * MT + p;
      xn2 = xyt[p2 * 3 + 0];
      yn2 = xyt[p2 * 3 + 1];
      tn2 = xyt[p2 * 3 + 2] * rfn;
    }
    __syncthreads();
    // L1: feat(32)->h1(64): actS.feat -> actB NK2
    layer_fp<1, 2, 1, 2, true>(actS + 16384, actB, wf1, fb1, wid & 3, (wid >> 2) * 2, lane);
    __syncthreads();
    // L2: h1->h2(64): actB -> actS NK4 frags 0-1 (pe frags 2-3 preserved)
    layer_fp<2, 4, 1, 2, true>(actB, actS, wf2, fb2, wid & 3, (wid >> 2) * 2, lane);
    __syncthreads();
    // L3: [h2|pe](128)->z1(256): actS NK4 -> actB NK8
    layer_fp<4, 8, 2, 4, true>(actS, actB, wf3, b1, wid * 2, 0, lane);
    __syncthreads();
    // L4: z1->z2(256): actB -> actS NK8
    layer_fp<8, 8, 2, 4, true>(actB, actS, wf4, b2, wid * 2, 0, lane);
    __syncthreads();
    // L5: z2->z3(256): actS -> actB NK8
    layer_fp<8, 8, 2, 4, true>(actS, actB, wf5, b3, wid * 2, 0, lane);
    __syncthreads();
    // L6: z3(256)->3 (pad 16), sigmoid, store. Waves 0..3 own the 4 point-groups.
    if (wid < 4) {
      const int l15 = lane & 15, lhi = lane >> 4;
      const char* rb = actB + lane * 16 + wid * 8192;
      f32x4 acc = {0.f, 0.f, 0.f, 0.f};
#pragma unroll
      for (int ks = 0; ks < 8; ++ks) {
        const bf16x8 wa = __builtin_bit_cast(bf16x8, wf6[ks * 64 + lane]);
        const bf16x8 b =
            __builtin_bit_cast(bf16x8, *reinterpret_cast<const uint4*>(rb + (ks << 10)));
        acc = __builtin_amdgcn_mfma_f32_16x16x32_bf16(wa, b, acc, 0, 0, 0);
      }
      if (lhi == 0) {
        const size_t pgl = (size_t)(tbase + it) * MT + wid * 16 + l15;
#pragma unroll
        for (int i = 0; i < 3; ++i) {
          const float v = acc[i] + b4[i];
          out[pgl * 3 + i] = 1.f / (1.f + expf(-v));
        }
      }
    }
    // ---- shift pipeline coords
    x = xn; y = yn; t = tn;
    xn = xn2; yn = yn2; tn = tn2;
    // no barrier needed here: next combine/pos-enc write actS; L6 reads actB;
    // the pre-L1 barrier orders actB writes vs L6 reads.
  }
}

// ================= fallback (fp32 weights, direct plane sampling) =============
__device__ __forceinline__ int swz(int row, int colbyte) {
  return row * 512 + (colbyte ^ ((row & 31) << 4));
}
__device__ __forceinline__ void st_act(unsigned short* buf, int row, int col, float v) {
  buf[swz(row, col * 2) >> 1] = __builtin_bit_cast(unsigned short, (bf16_t)v);
}
__device__ __forceinline__ bf16x8 ld_frag(const unsigned short* buf, int row, int kbyte) {
  const uint4 u =
      *reinterpret_cast<const uint4*>(reinterpret_cast<const char*>(buf) + swz(row, kbyte));
  return __builtin_bit_cast(bf16x8, u);
}
__device__ __forceinline__ void sample8_f(const float* __restrict__ pl, int Hd, int Wd, float u,
                                          float v, int cgrp, float* o) {
  float ix = fminf(fmaxf(u * (float)Wd - 0.5f, 0.f), (float)Wd - 1.f);
  float iy = fminf(fmaxf(v * (float)Hd - 0.5f, 0.f), (float)Hd - 1.f);
  float x0f = floorf(ix), y0f = floorf(iy);
  float wx = ix - x0f, wy = iy - y0f;
  int x0 = (int)x0f, y0 = (int)y0f;
  int x1 = min(x0 + 1, Wd - 1), y1 = min(y0 + 1, Hd - 1);
  float w00 = (1.f - wx) * (1.f - wy), w01 = wx * (1.f - wy);
  float w10 = (1.f - wx) * wy, w11 = wx * wy;
  const size_t HW = (size_t)Hd * Wd;
#pragma unroll
  for (int i = 0; i < 8; ++i) {
    const float* bc = pl + (size_t)(cgrp + i) * HW;
    float a = bc[(size_t)y0 * Wd + x0], b = bc[(size_t)y0 * Wd + x1];
    float c = bc[(size_t)y1 * Wd + x0], d = bc[(size_t)y1 * Wd + x1];
    o[i] = a * w00 + b * w01 + c * w10 + d * w11;
  }
}

template <int KSTEPS, int NCPW, bool RELU>
__device__ __forceinline__ void mfma_layer_fb(const unsigned short* inb, unsigned short* outb,
                                              const float* __restrict__ Wg,
                                              const float* __restrict__ bg, int N, int Kmax,
                                              int wid, int lane) {
  const int l15 = lane & 15;
  const int lhi = lane >> 4;
#pragma unroll
  for (int t = 0; t < NCPW; ++t) {
    const int nc = wid * NCPW + t;
    const int col = nc * 16 + l15;
    const float bias = bg[col];
    bf16x8 bfrag[KSTEPS];
#pragma unroll
    for (int ks = 0; ks < KSTEPS; ++ks) {
#pragma unroll
      for (int j = 0; j < 8; ++j) {
        const int k = ks * 32 + lhi * 8 + j;
        float wv = (k < Kmax) ? Wg[(size_t)k * N + col] : 0.0f;
        bfrag[ks][j] = (bf16_t)wv;
      }
    }
#pragma unroll
    for (int m = 0; m < 4; ++m) {
      f32x4 acc = {0.f, 0.f, 0.f, 0.f};
#pragma unroll
      for (int ks = 0; ks < KSTEPS; ++ks) {
        bf16x8 a = ld_frag(inb, m * 16 + l15, ks * 64 + lhi * 16);
        acc = __builtin_amdgcn_mfma_f32_16x16x32_bf16(a, bfrag[ks], acc, 0, 0, 0);
      }
      const int r0 = m * 16 + lhi * 4;
#pragma unroll
      for (int i = 0; i < 4; ++i) {
        float v = acc[i] + bias;
        if (RELU) v = fmaxf(v, 0.f);
        st_act(outb, r0 + i, col, v);
      }
    }
  }
}

__global__ __launch_bounds__(256) void KPlanes_fused_fb(
    const float* __restrict__ xyt, const float* __restrict__ yx, const float* __restrict__ xt,
    const float* __restrict__ yt, const float* __restrict__ fw1, const float* __restrict__ fb1,
    const float* __restrict__ fw2, const float* __restrict__ fb2, const float* __restrict__ w1,
    const float* __restrict__ b1, const float* __restrict__ w2, const float* __restrict__ b2,
    const float* __restrict__ w3, const float* __restrict__ b3, const float* __restrict__ w4,
    const float* __restrict__ b4, const int* __restrict__ fnum_p, float* __restrict__ out) {
  __shared__ unsigned short actA[64 * 256];
  __shared__ unsigned short actB[64 * 256];
  const int tid = threadIdx.x;
  const int lane = tid & 63;
  const int wid = tid >> 6;
  const float fnum = (float)(*fnum_p);
  {
    const int p = tid >> 2;
    const int cgrp = (tid & 3) * 8;
    const int pg = blockIdx.x * 64 + p;
    float x = xyt[pg * 3 + 0];
    float y = xyt[pg * 3 + 1];
    float t = xyt[pg * 3 + 2] / fnum;
    float syx[8], sxt[8], syt[8];
    sample8_f(yx, 540, 960, y, x, cgrp, syx);
    sample8_f(xt, 960, 300, x, t, cgrp, sxt);
    sample8_f(yt, 540, 300, y, t, cgrp, syt);
#pragma unroll
    for (int i = 0; i < 8; ++i) st_act(actA, p, cgrp + i, syx[i] * sxt[i] * syt[i]);
  }
  __syncthreads();
  mfma_layer_fb<1, 1, true>(actA, actB, fw1, fb1, 64, 32, wid, lane);
  __syncthreads();
  mfma_layer_fb<2, 1, true>(actB, actA, fw2, fb2, 64, 64, wid, lane);
  if (tid < 64) {
    const int pg = blockIdx.x * 64 + tid;
    float px = xyt[pg * 3 + 0];
    float py = xyt[pg * 3 + 1];
    float pt = xyt[pg * 3 + 2] / fnum;
    st_act(actA, tid, 64, py);
    st_act(actA, tid, 65, px);
    float sc = 1.f;
#pragma unroll
    for (int j = 0; j < 10; ++j) {
      st_act(actA, tid, 66 + j * 4 + 0, sinf(sc * py));
      st_act(actA, tid, 66 + j * 4 + 1, sinf(sc * px));
      st_act(actA, tid, 66 + j * 4 + 2, cosf(sc * py));
      st_act(actA, tid, 66 + j * 4 + 3, cosf(sc * px));
      sc *= 2.f;
    }
    st_act(actA, tid, 106, pt);
    sc = 1.f;
#pragma unroll
    for (int j = 0; j < 6; ++j) {
      st_act(actA, tid, 107 + j * 2, sinf(sc * pt));
      st_act(actA, tid, 108 + j * 2, cosf(sc * pt));
      sc *= 2.f;
    }
#pragma unroll
    for (int c = 119; c < 128; ++c) st_act(actA, tid, c, 0.f);
  }
  __syncthreads();
  mfma_layer_fb<4, 4, true>(actA, actB, w1, b1, 256, 119, wid, lane);
  __syncthreads();
  mfma_layer_fb<8, 4, true>(actB, actA, w2, b2, 256, 256, wid, lane);
  __syncthreads();
  mfma_layer_fb<8, 4, true>(actA, actB, w3, b3, 256, 256, wid, lane);
  __syncthreads();
  {
    const int p = tid >> 2, c = tid & 3;
    if (c < 3) {
      float acc = 0.f;
#pragma unroll
      for (int k0 = 0; k0 < 256; k0 += 8) {
        int b = swz(p, k0 * 2);
        uint4 u = *reinterpret_cast<const uint4*>(reinterpret_cast<const char*>(actB) + b);
        bf16x8 z = __builtin_bit_cast(bf16x8, u);
#pragma unroll
        for (int j = 0; j < 8; ++j) acc += (float)z[j] * w4[(k0 + j) * 3 + c];
      }
      acc += b4[c];
      out[(size_t)(blockIdx.x * 64 + p) * 3 + c] = 1.f / (1.f + expf(-acc));
    }
  }
}

extern "C" void kernel_launch(void* const* d_in, const int* in_sizes, int n_in, void* d_out,
                              int out_size, void* d_ws, size_t ws_size, hipStream_t stream) {
  const float* xyt = (const float*)d_in[0];
  const float* yx = (const float*)d_in[1];
  const float* xt = (const float*)d_in[2];
  const float* yt = (const float*)d_in[3];
  const float* fw1 = (const float*)d_in[4];
  const float* fb1 = (const float*)d_in[5];
  const float* fw2 = (const float*)d_in[6];
  const float* fb2 = (const float*)d_in[7];
  const float* w1 = (const float*)d_in[8];
  const float* b1 = (const float*)d_in[9];
  const float* w2 = (const float*)d_in[10];
  const float* b2 = (const float*)d_in[11];
  const float* w3 = (const float*)d_in[12];
  const float* b3 = (const float*)d_in[13];
  const float* w4 = (const float*)d_in[14];
  const float* b4 = (const float*)d_in[15];
  const int* fnum = (const int*)d_in[16];
  float* out = (float*)d_out;

  const int hw_yx = 540 * 960, hw_xt = 960 * 300, hw_yt = 540 * 300;
  const size_t plane_bytes = ((size_t)hw_yx + hw_xt + hw_yt) * 64;  // fp16, 64B/site
  const size_t wfrag_bytes = (size_t)340 * 64 * sizeof(uint4);
  const size_t need = plane_bytes + wfrag_bytes;

  char* ws = (char*)d_ws;
  uint2* yx_h = (uint2*)ws;
  uint2* xt_h = (uint2*)(ws + (size_t)hw_yx * 64);
  uint2* yt_h = (uint2*)(ws + (size_t)(hw_yx + hw_xt) * 64);
  uint4* wbase = (uint4*)(ws + plane_bytes);
  uint4* wf1 = wbase + 0 * 64;
  uint4* wf2 = wbase + 4 * 64;
  uint4* wf3 = wbase + 12 * 64;
  uint4* wf4 = wbase + 76 * 64;
  uint4* wf5 = wbase + 204 * 64;
  uint4* wf6 = wbase + 332 * 64;

  if (ws_size >= need) {
    const int nb_tr = 2025 + 1125 + 633;
    KPlanes_tr3<<<nb_tr, 256, 0, stream>>>(yx, xt, yt, (uint4*)yx_h, (uint4*)xt_h, (uint4*)yt_h);
    KPlanes_packall<<<85, 256, 0, stream>>>(fw1, fw2, w1, w2, w3, w4, wbase);
    KPlanes_fusedP<<<NPBLK, NTHR, 0, stream>>>(xyt, yx_h, xt_h, yt_h, wf1, fb1, wf2, fb2, wf3, b1,
                                               wf4, b2, wf5, b3, wf6, b4, fnum, out);
  } else {
    KPlanes_fused_fb<<<1048576 / 64, 256, 0, stream>>>(xyt, yx, xt, yt, fw1, fb1, fw2, fb2, w1,
                                                       b1, w2, b2, w3, b3, w4, b4, fnum, out);
  }
}

// Round 11
// 473.795 us; speedup vs baseline: 3.8540x; 3.8540x over previous
//
#include <hip/hip_runtime.h>

typedef __bf16 bf16_t;
typedef __bf16 bf16x8 __attribute__((ext_vector_type(8)));
typedef _Float16 h16x4 __attribute__((ext_vector_type(4)));
typedef _Float16 h16x8 __attribute__((ext_vector_type(8)));
typedef unsigned short u16x8 __attribute__((ext_vector_type(8)));
typedef float f32x4 __attribute__((ext_vector_type(4)));

#define MT 64
#define NTHR 512
#define NBLK (1048576 / MT)

// ---------------- fragment-native LDS layout ----------------------------------
// value(point p, neuron n): byte (pg*NK + (n>>5))*1024 + ((n>>3)&3)*256 + (p&15)*16 + (n&7)*2
// B-fragment (pgroup, kstep) = contiguous 1KB at (pg*NK + ks)*1024 + lane*16.
__device__ __forceinline__ int fragoff(int NK, int pg, int n, int p15) {
  return ((pg * NK + (n >> 5)) << 10) + (((n >> 3) & 3) << 8) + (p15 << 4) + ((n & 7) << 1);
}
__device__ __forceinline__ void st_frag1(char* buf, int NK, int pg, int n, int p15, float v) {
  *reinterpret_cast<_Float16*>(buf + fragoff(NK, pg, n, p15)) = (_Float16)v;
}
__device__ __forceinline__ unsigned pk2(float a, float b) {
  return __builtin_bit_cast(unsigned, __builtin_amdgcn_cvt_pkrtz(a, b));
}
__device__ __forceinline__ void st_frag4(char* buf, int NK, int pg, int n, int p15, float v0,
                                         float v1, float v2, float v3) {
  *reinterpret_cast<uint2*>(buf + fragoff(NK, pg, n, p15)) = uint2{pk2(v0, v1), pk2(v2, v3)};
}

// ---------- prologue 1: transpose all 3 planes (32,H,W) fp32 -> (H*W,32) fp16 --
__global__ void KPlanes_tr3(const float* __restrict__ yx, const float* __restrict__ xt,
                            const float* __restrict__ yt, uint4* __restrict__ d0,
                            uint4* __restrict__ d1, uint4* __restrict__ d2) {
  const int HW0 = 518400, HW1 = 288000, HW2 = 162000;
  const int NB0 = 2025, NB1 = 1125;
  const int b = blockIdx.x;
  const float* src;
  uint4* dst;
  int HW, s;
  if (b < NB0) {
    src = yx; dst = d0; HW = HW0; s = b * 256 + threadIdx.x;
  } else if (b < NB0 + NB1) {
    src = xt; dst = d1; HW = HW1; s = (b - NB0) * 256 + threadIdx.x;
  } else {
    src = yt; dst = d2; HW = HW2; s = (b - NB0 - NB1) * 256 + threadIdx.x;
  }
  if (s >= HW) return;
#pragma unroll
  for (int g = 0; g < 4; ++g) {
    u16x8 v;
#pragma unroll
    for (int j = 0; j < 8; ++j) {
      const float w = src[(size_t)(g * 8 + j) * HW + s];
      v[j] = __builtin_bit_cast(unsigned short, (_Float16)w);
    }
    dst[(size_t)s * 4 + g] = __builtin_bit_cast(uint4, v);
  }
}

// ---------- prologue 2: pack ALL fp32 weights into fp16 MFMA fragments --------
// lane holds col(neuron)=g*16+(lane&15), k=ks*32+(lane>>4)*8+j  (A-operand)
__global__ void KPlanes_packall(const float* __restrict__ fw1, const float* __restrict__ fw2,
                                const float* __restrict__ w1, const float* __restrict__ w2,
                                const float* __restrict__ w3, const float* __restrict__ w4,
                                uint4* __restrict__ dst) {
  const int F = blockIdx.x * 4 + (threadIdx.x >> 6);
  const int lane = threadIdx.x & 63;
  if (F >= 340) return;
  const float* W;
  int N, K, KS, fbase;
  if (F < 4)        { W = fw1; N = 64;  K = 32;  KS = 1; fbase = 0; }
  else if (F < 12)  { W = fw2; N = 64;  K = 64;  KS = 2; fbase = 4; }
  else if (F < 76)  { W = w1;  N = 256; K = 119; KS = 4; fbase = 12; }
  else if (F < 204) { W = w2;  N = 256; K = 256; KS = 8; fbase = 76; }
  else if (F < 332) { W = w3;  N = 256; K = 256; KS = 8; fbase = 204; }
  else              { W = w4;  N = 3;   K = 256; KS = 8; fbase = 332; }
  const int f = F - fbase;
  const int g = f / KS, ks = f - g * KS;
  const int col = g * 16 + (lane & 15);
  u16x8 v;
#pragma unroll
  for (int j = 0; j < 8; ++j) {
    const int k = ks * 32 + (lane >> 4) * 8 + j;
    const float w = (k < K && col < N) ? W[(size_t)k * N + col] : 0.0f;
    v[j] = __builtin_bit_cast(unsigned short, (_Float16)w);
  }
  dst[(size_t)F * 64 + lane] = __builtin_bit_cast(uint4, v);
}

// ---------- fp16 bilinear sample, 4 channels per thread -----------------------
struct Smp4 {
  uint2 c00, c01, c10, c11;
  float w00, w01, w10, w11;
};
__device__ __forceinline__ Smp4 sample_ld4(const uint2* __restrict__ plt, int Hd, int Wd, float u,
                                           float v, int q) {
  Smp4 s;
  float ix = fminf(fmaxf(u * (float)Wd - 0.5f, 0.f), (float)Wd - 1.f);
  float iy = fminf(fmaxf(v * (float)Hd - 0.5f, 0.f), (float)Hd - 1.f);
  float x0f = floorf(ix), y0f = floorf(iy);
  float wx = ix - x0f, wy = iy - y0f;
  int x0 = (int)x0f, y0 = (int)y0f;
  int x1 = min(x0 + 1, Wd - 1), y1 = min(y0 + 1, Hd - 1);
  s.w00 = (1.f - wx) * (1.f - wy);
  s.w01 = wx * (1.f - wy);
  s.w10 = (1.f - wx) * wy;
  s.w11 = wx * wy;
  const size_t r0 = (size_t)y0 * Wd, r1 = (size_t)y1 * Wd;
  s.c00 = plt[(r0 + x0) * 8 + q];
  s.c01 = plt[(r0 + x1) * 8 + q];
  s.c10 = plt[(r1 + x0) * 8 + q];
  s.c11 = plt[(r1 + x1) * 8 + q];
  return s;
}
// packed-f16 combine: 4 channels via v_pk_fma_f16, no f32 round-trip
__device__ __forceinline__ h16x4 smp_combine4h(const Smp4& s) {
  const h16x4 a = __builtin_bit_cast(h16x4, s.c00);
  const h16x4 b = __builtin_bit_cast(h16x4, s.c01);
  const h16x4 c = __builtin_bit_cast(h16x4, s.c10);
  const h16x4 d = __builtin_bit_cast(h16x4, s.c11);
  const _Float16 w00 = (_Float16)s.w00, w01 = (_Float16)s.w01;
  const _Float16 w10 = (_Float16)s.w10, w11 = (_Float16)s.w11;
  return a * w00 + b * w01 + c * w10 + d * w11;
}

// ---------- ping-pong MFMA layer on fragment-native LDS (fp16) ----------------
// D = W(A) x act(B). Reads: contiguous b128 at lane*16 + imm offset. Writes:
// D lane = point, 4 consecutive neurons -> one 8B store (2x cvt_pkrtz).
template <int KS, int NKOUT, int NT, int MTPW, bool RELU>
__device__ __forceinline__ void layer_fp(const char* in, char* outb, const uint4* __restrict__ Wf,
                                         const float* __restrict__ bg, int gbase, int moff,
                                         int lane) {
  const int l15 = lane & 15, lhi = lane >> 4;
  const char* rb = in + lane * 16 + moff * (KS << 10);
  f32x4 acc[MTPW][NT];
#pragma unroll
  for (int m = 0; m < MTPW; ++m)
#pragma unroll
    for (int t = 0; t < NT; ++t) acc[m][t] = f32x4{0.f, 0.f, 0.f, 0.f};
#pragma unroll
  for (int ks = 0; ks < KS; ++ks) {
    h16x8 wa[NT];
#pragma unroll
    for (int t = 0; t < NT; ++t)
      wa[t] = __builtin_bit_cast(h16x8, Wf[(size_t)((gbase + t) * KS + ks) * 64 + lane]);
#pragma unroll
    for (int m = 0; m < MTPW; ++m) {
      const uint4 u = *reinterpret_cast<const uint4*>(rb + ((m * KS + ks) << 10));
      const h16x8 b = __builtin_bit_cast(h16x8, u);
#pragma unroll
      for (int t = 0; t < NT; ++t)
        acc[m][t] = __builtin_amdgcn_mfma_f32_16x16x32_f16(wa[t], b, acc[m][t], 0, 0, 0);
    }
  }
#pragma unroll
  for (int t = 0; t < NT; ++t) {
    const int ncol = (gbase + t) * 16 + lhi * 4;
    const float4 bb = *reinterpret_cast<const float4*>(&bg[ncol]);
#pragma unroll
    for (int m = 0; m < MTPW; ++m) {
      float v0 = acc[m][t][0] + bb.x, v1 = acc[m][t][1] + bb.y;
      float v2 = acc[m][t][2] + bb.z, v3 = acc[m][t][3] + bb.w;
      if (RELU) {
        v0 = fmaxf(v0, 0.f); v1 = fmaxf(v1, 0.f);
        v2 = fmaxf(v2, 0.f); v3 = fmaxf(v3, 0.f);
      }
      st_frag4(outb, NKOUT, moff + m, ncol, l15, v0, v1, v2, v3);
    }
  }
}

// ---------- main fused kernel: 64 pts/block, 8 waves, 64 KB LDS, 2 blk/CU -----
// actS: [0,16K) = L3-input NK=4 (h2 frags 0-1, posenc frags 2-3); [16K,20K) = feat NK=1.
__global__ __launch_bounds__(NTHR, 4) void KPlanes_fusedA(
    const float* __restrict__ xyt, const uint2* __restrict__ yx_h, const uint2* __restrict__ xt_h,
    const uint2* __restrict__ yt_h, const uint4* __restrict__ wf1, const float* __restrict__ fb1,
    const uint4* __restrict__ wf2, const float* __restrict__ fb2, const uint4* __restrict__ wf3,
    const float* __restrict__ b1, const uint4* __restrict__ wf4, const float* __restrict__ b2,
    const uint4* __restrict__ wf5, const float* __restrict__ b3, const uint4* __restrict__ wf6,
    const float* __restrict__ b4, const int* __restrict__ fnum_p, float* __restrict__ out) {
  __shared__ char actS[32768];
  __shared__ char actB[32768];
  const int tid = threadIdx.x;
  const int lane = tid & 63;
  const int wid = tid >> 6;
  const float rfn = 1.0f / (float)(*fnum_p);

  // ---- phase 0: gather (8 thr/point, 4 ch each) + pos-enc
  {
    const int p = tid >> 3;
    const int q = tid & 7;
    const int pg = p >> 4, p15 = p & 15;
    const int pgl = blockIdx.x * MT + p;
    const float x = xyt[pgl * 3 + 0];
    const float y = xyt[pgl * 3 + 1];
    const float t = xyt[pgl * 3 + 2] * rfn;
    Smp4 sYX = sample_ld4(yx_h, 540, 960, y, x, q);
    Smp4 sXT = sample_ld4(xt_h, 960, 300, x, t, q);
    Smp4 sYT = sample_ld4(yt_h, 540, 300, y, t, q);
    // pos-enc into NK=4 frags of actS (neurons 64..118), zeros 119..127
    if (q == 4) {
      st_frag1(actS, 4, pg, 64, p15, y);
      float sj, cj;
      sincosf(y, &sj, &cj);
#pragma unroll
      for (int j = 0; j < 10; ++j) {
        st_frag1(actS, 4, pg, 66 + j * 4, p15, sj);
        st_frag1(actS, 4, pg, 68 + j * 4, p15, cj);
        const float ns = 2.f * sj * cj;
        cj = fmaf(-2.f * sj, sj, 1.f);
        sj = ns;
      }
    } else if (q == 5) {
      st_frag1(actS, 4, pg, 65, p15, x);
      float sj, cj;
      sincosf(x, &sj, &cj);
#pragma unroll
      for (int j = 0; j < 10; ++j) {
        st_frag1(actS, 4, pg, 67 + j * 4, p15, sj);
        st_frag1(actS, 4, pg, 69 + j * 4, p15, cj);
        const float ns = 2.f * sj * cj;
        cj = fmaf(-2.f * sj, sj, 1.f);
        sj = ns;
      }
    } else if (q == 6) {
      st_frag1(actS, 4, pg, 106, p15, t);
      float sj, cj;
      sincosf(t, &sj, &cj);
#pragma unroll
      for (int j = 0; j < 6; ++j) {
        st_frag1(actS, 4, pg, 107 + 2 * j, p15, sj);
        st_frag1(actS, 4, pg, 108 + 2 * j, p15, cj);
        const float ns = 2.f * sj * cj;
        cj = fmaf(-2.f * sj, sj, 1.f);
        sj = ns;
      }
    } else if (q == 7) {
      st_frag1(actS, 4, pg, 119, p15, 0.f);
      *reinterpret_cast<uint4*>(actS + fragoff(4, pg, 120, p15)) = uint4{0u, 0u, 0u, 0u};
    }
    // packed-f16 combine + triple product, direct 8B store
    const h16x4 fa = smp_combine4h(sYX);
    const h16x4 fb = smp_combine4h(sXT);
    const h16x4 fc = smp_combine4h(sYT);
    const h16x4 prod = fa * fb * fc;
    *reinterpret_cast<uint2*>(actS + 16384 + fragoff(1, pg, q * 4, p15)) =
        __builtin_bit_cast(uint2, prod);
  }
  __syncthreads();
  // L1: feat(32)->h1(64): actS.feat -> actB NK2. 4 n-groups x 2 m-pairs over 8 waves.
  layer_fp<1, 2, 1, 2, true>(actS + 16384, actB, wf1, fb1, wid & 3, (wid >> 2) * 2, lane);
  __syncthreads();
  // L2: h1->h2(64): actB -> actS NK4 frags 0-1 (posenc frags 2-3 untouched)
  layer_fp<2, 4, 1, 2, true>(actB, actS, wf2, fb2, wid & 3, (wid >> 2) * 2, lane);
  __syncthreads();
  // L3: [h2|pe](128)->z1(256): actS NK4 -> actB NK8. wave: 2 n-groups, 4 m-groups.
  layer_fp<4, 8, 2, 4, true>(actS, actB, wf3, b1, wid * 2, 0, lane);
  __syncthreads();
  // L4: z1->z2(256): actB -> actS NK8 (overwrites all of actS)
  layer_fp<8, 8, 2, 4, true>(actB, actS, wf4, b2, wid * 2, 0, lane);
  __syncthreads();
  // L5: z2->z3(256): actS -> actB
  layer_fp<8, 8, 2, 4, true>(actS, actB, wf5, b3, wid * 2, 0, lane);
  __syncthreads();
  // L6: z3(256)->3 (pad 16), sigmoid, store. Waves 0..3 own the 4 point-groups.
  if (wid < 4) {
    const int l15 = lane & 15, lhi = lane >> 4;
    const char* rb = actB + lane * 16 + wid * 8192;
    f32x4 acc = {0.f, 0.f, 0.f, 0.f};
#pragma unroll
    for (int ks = 0; ks < 8; ++ks) {
      const h16x8 wa = __builtin_bit_cast(h16x8, wf6[ks * 64 + lane]);
      const h16x8 b = __builtin_bit_cast(h16x8, *reinterpret_cast<const uint4*>(rb + (ks << 10)));
      acc = __builtin_amdgcn_mfma_f32_16x16x32_f16(wa, b, acc, 0, 0, 0);
    }
    if (lhi == 0) {
      const size_t pgl = (size_t)blockIdx.x * MT + wid * 16 + l15;
#pragma unroll
      for (int i = 0; i < 3; ++i) {
        const float v = acc[i] + b4[i];
        out[pgl * 3 + i] = 1.f / (1.f + expf(-v));
      }
    }
  }
}

// ================= fallback (fp32 weights, direct plane sampling) =============
__device__ __forceinline__ int swz(int row, int colbyte) {
  return row * 512 + (colbyte ^ ((row & 31) << 4));
}
__device__ __forceinline__ void st_act(unsigned short* buf, int row, int col, float v) {
  buf[swz(row, col * 2) >> 1] = __builtin_bit_cast(unsigned short, (bf16_t)v);
}
__device__ __forceinline__ bf16x8 ld_frag(const unsigned short* buf, int row, int kbyte) {
  const uint4 u =
      *reinterpret_cast<const uint4*>(reinterpret_cast<const char*>(buf) + swz(row, kbyte));
  return __builtin_bit_cast(bf16x8, u);
}
__device__ __forceinline__ void sample8_f(const float* __restrict__ pl, int Hd, int Wd, float u,
                                          float v, int cgrp, float* o) {
  float ix = fminf(fmaxf(u * (float)Wd - 0.5f, 0.f), (float)Wd - 1.f);
  float iy = fminf(fmaxf(v * (float)Hd - 0.5f, 0.f), (float)Hd - 1.f);
  float x0f = floorf(ix), y0f = floorf(iy);
  float wx = ix - x0f, wy = iy - y0f;
  int x0 = (int)x0f, y0 = (int)y0f;
  int x1 = min(x0 + 1, Wd - 1), y1 = min(y0 + 1, Hd - 1);
  float w00 = (1.f - wx) * (1.f - wy), w01 = wx * (1.f - wy);
  float w10 = (1.f - wx) * wy, w11 = wx * wy;
  const size_t HW = (size_t)Hd * Wd;
#pragma unroll
  for (int i = 0; i < 8; ++i) {
    const float* bc = pl + (size_t)(cgrp + i) * HW;
    float a = bc[(size_t)y0 * Wd + x0], b = bc[(size_t)y0 * Wd + x1];
    float c = bc[(size_t)y1 * Wd + x0], d = bc[(size_t)y1 * Wd + x1];
    o[i] = a * w00 + b * w01 + c * w10 + d * w11;
  }
}

template <int KSTEPS, int NCPW, bool RELU>
__device__ __forceinline__ void mfma_layer_fb(const unsigned short* inb, unsigned short* outb,
                                              const float* __restrict__ Wg,
                                              const float* __restrict__ bg, int N, int Kmax,
                                              int wid, int lane) {
  const int l15 = lane & 15;
  const int lhi = lane >> 4;
#pragma unroll
  for (int t = 0; t < NCPW; ++t) {
    const int nc = wid * NCPW + t;
    const int col = nc * 16 + l15;
    const float bias = bg[col];
    bf16x8 bfrag[KSTEPS];
#pragma unroll
    for (int ks = 0; ks < KSTEPS; ++ks) {
#pragma unroll
      for (int j = 0; j < 8; ++j) {
        const int k = ks * 32 + lhi * 8 + j;
        float wv = (k < Kmax) ? Wg[(size_t)k * N + col] : 0.0f;
        bfrag[ks][j] = (bf16_t)wv;
      }
    }
#pragma unroll
    for (int m = 0; m < 4; ++m) {
      f32x4 acc = {0.f, 0.f, 0.f, 0.f};
#pragma unroll
      for (int ks = 0; ks < KSTEPS; ++ks) {
        bf16x8 a = ld_frag(inb, m * 16 + l15, ks * 64 + lhi * 16);
        acc = __builtin_amdgcn_mfma_f32_16x16x32_bf16(a, bfrag[ks], acc, 0, 0, 0);
      }
      const int r0 = m * 16 + lhi * 4;
#pragma unroll
      for (int i = 0; i < 4; ++i) {
        float v = acc[i] + bias;
        if (RELU) v = fmaxf(v, 0.f);
        st_act(outb, r0 + i, col, v);
      }
    }
  }
}

__global__ __launch_bounds__(256) void KPlanes_fused_fb(
    const float* __restrict__ xyt, const float* __restrict__ yx, const float* __restrict__ xt,
    const float* __restrict__ yt, const float* __restrict__ fw1, const float* __restrict__ fb1,
    const float* __restrict__ fw2, const float* __restrict__ fb2, const float* __restrict__ w1,
    const float* __restrict__ b1, const float* __restrict__ w2, const float* __restrict__ b2,
    const float* __restrict__ w3, const float* __restrict__ b3, const float* __restrict__ w4,
    const float* __restrict__ b4, const int* __restrict__ fnum_p, float* __restrict__ out) {
  __shared__ unsigned short actA[64 * 256];
  __shared__ unsigned short actB[64 * 256];
  const int tid = threadIdx.x;
  const int lane = tid & 63;
  const int wid = tid >> 6;
  const float fnum = (float)(*fnum_p);
  {
    const int p = tid >> 2;
    const int cgrp = (tid & 3) * 8;
    const int pg = blockIdx.x * 64 + p;
    float x = xyt[pg * 3 + 0];
    float y = xyt[pg * 3 + 1];
    float t = xyt[pg * 3 + 2] / fnum;
    float syx[8], sxt[8], syt[8];
    sample8_f(yx, 540, 960, y, x, cgrp, syx);
    sample8_f(xt, 960, 300, x, t, cgrp, sxt);
    sample8_f(yt, 540, 300, y, t, cgrp, syt);
#pragma unroll
    for (int i = 0; i < 8; ++i) st_act(actA, p, cgrp + i, syx[i] * sxt[i] * syt[i]);
  }
  __syncthreads();
  mfma_layer_fb<1, 1, true>(actA, actB, fw1, fb1, 64, 32, wid, lane);
  __syncthreads();
  mfma_layer_fb<2, 1, true>(actB, actA, fw2, fb2, 64, 64, wid, lane);
  if (tid < 64) {
    const int pg = blockIdx.x * 64 + tid;
    float px = xyt[pg * 3 + 0];
    float py = xyt[pg * 3 + 1];
    float pt = xyt[pg * 3 + 2] / fnum;
    st_act(actA, tid, 64, py);
    st_act(actA, tid, 65, px);
    float sc = 1.f;
#pragma unroll
    for (int j = 0; j < 10; ++j) {
      st_act(actA, tid, 66 + j * 4 + 0, sinf(sc * py));
      st_act(actA, tid, 66 + j * 4 + 1, sinf(sc * px));
      st_act(actA, tid, 66 + j * 4 + 2, cosf(sc * py));
      st_act(actA, tid, 66 + j * 4 + 3, cosf(sc * px));
      sc *= 2.f;
    }
    st_act(actA, tid, 106, pt);
    sc = 1.f;
#pragma unroll
    for (int j = 0; j < 6; ++j) {
      st_act(actA, tid, 107 + j * 2, sinf(sc * pt));
      st_act(actA, tid, 108 + j * 2, cosf(sc * pt));
      sc *= 2.f;
    }
#pragma unroll
    for (int c = 119; c < 128; ++c) st_act(actA, tid, c, 0.f);
  }
  __syncthreads();
  mfma_layer_fb<4, 4, true>(actA, actB, w1, b1, 256, 119, wid, lane);
  __syncthreads();
  mfma_layer_fb<8, 4, true>(actB, actA, w2, b2, 256, 256, wid, lane);
  __syncthreads();
  mfma_layer_fb<8, 4, true>(actA, actB, w3, b3, 256, 256, wid, lane);
  __syncthreads();
  {
    const int p = tid >> 2, c = tid & 3;
    if (c < 3) {
      float acc = 0.f;
#pragma unroll
      for (int k0 = 0; k0 < 256; k0 += 8) {
        int b = swz(p, k0 * 2);
        uint4 u = *reinterpret_cast<const uint4*>(reinterpret_cast<const char*>(actB) + b);
        bf16x8 z = __builtin_bit_cast(bf16x8, u);
#pragma unroll
        for (int j = 0; j < 8; ++j) acc += (float)z[j] * w4[(k0 + j) * 3 + c];
      }
      acc += b4[c];
      out[(size_t)(blockIdx.x * 64 + p) * 3 + c] = 1.f / (1.f + expf(-acc));
    }
  }
}

extern "C" void kernel_launch(void* const* d_in, const int* in_sizes, int n_in, void* d_out,
                              int out_size, void* d_ws, size_t ws_size, hipStream_t stream) {
  const float* xyt = (const float*)d_in[0];
  const float* yx = (const float*)d_in[1];
  const float* xt = (const float*)d_in[2];
  const float* yt = (const float*)d_in[3];
  const float* fw1 = (const float*)d_in[4];
  const float* fb1 = (const float*)d_in[5];
  const float* fw2 = (const float*)d_in[6];
  const float* fb2 = (const float*)d_in[7];
  const float* w1 = (const float*)d_in[8];
  const float* b1 = (const float*)d_in[9];
  const float* w2 = (const float*)d_in[10];
  const float* b2 = (const float*)d_in[11];
  const float* w3 = (const float*)d_in[12];
  const float* b3 = (const float*)d_in[13];
  const float* w4 = (const float*)d_in[14];
  const float* b4 = (const float*)d_in[15];
  const int* fnum = (const int*)d_in[16];
  float* out = (float*)d_out;

  const int hw_yx = 540 * 960, hw_xt = 960 * 300, hw_yt = 540 * 300;
  const size_t plane_bytes = ((size_t)hw_yx + hw_xt + hw_yt) * 64;  // fp16, 64B/site
  const size_t wfrag_bytes = (size_t)340 * 64 * sizeof(uint4);
  const size_t need = plane_bytes + wfrag_bytes;

  char* ws = (char*)d_ws;
  uint2* yx_h = (uint2*)ws;
  uint2* xt_h = (uint2*)(ws + (size_t)hw_yx * 64);
  uint2* yt_h = (uint2*)(ws + (size_t)(hw_yx + hw_xt) * 64);
  uint4* wbase = (uint4*)(ws + plane_bytes);
  uint4* wf1 = wbase + 0 * 64;
  uint4* wf2 = wbase + 4 * 64;
  uint4* wf3 = wbase + 12 * 64;
  uint4* wf4 = wbase + 76 * 64;
  uint4* wf5 = wbase + 204 * 64;
  uint4* wf6 = wbase + 332 * 64;

  if (ws_size >= need) {
    const int nb_tr = 2025 + 1125 + 633;
    KPlanes_tr3<<<nb_tr, 256, 0, stream>>>(yx, xt, yt, (uint4*)yx_h, (uint4*)xt_h, (uint4*)yt_h);
    KPlanes_packall<<<85, 256, 0, stream>>>(fw1, fw2, w1, w2, w3, w4, wbase);
    KPlanes_fusedA<<<NBLK, NTHR, 0, stream>>>(xyt, yx_h, xt_h, yt_h, wf1, fb1, wf2, fb2, wf3, b1,
                                              wf4, b2, wf5, b3, wf6, b4, fnum, out);
  } else {
    KPlanes_fused_fb<<<1048576 / 64, 256, 0, stream>>>(xyt, yx, xt, yt, fw1, fb1, fw2, fb2, w1,
                                                       b1, w2, b2, w3, b3, w4, b4, fnum, out);
  }
}

// Round 13
// 457.628 us; speedup vs baseline: 3.9901x; 1.0353x over previous
//
#include <hip/hip_runtime.h>

typedef __bf16 bf16_t;
typedef __bf16 bf16x8 __attribute__((ext_vector_type(8)));
typedef _Float16 h16x2 __attribute__((ext_vector_type(2)));
typedef _Float16 h16x4 __attribute__((ext_vector_type(4)));
typedef _Float16 h16x8 __attribute__((ext_vector_type(8)));
typedef unsigned short u16x8 __attribute__((ext_vector_type(8)));
typedef float f32x4 __attribute__((ext_vector_type(4)));

#define MT 64
#define NTHR 512
#define NBLK (1048576 / MT)

// ---------------- fragment-native LDS layout ----------------------------------
// value(point p, neuron n): byte (pg*NK + (n>>5))*1024 + ((n>>3)&3)*256 + (p&15)*16 + (n&7)*2
// B-fragment (pgroup, kstep) = contiguous 1KB at (pg*NK + ks)*1024 + lane*16.
__device__ __forceinline__ int fragoff(int NK, int pg, int n, int p15) {
  return ((pg * NK + (n >> 5)) << 10) + (((n >> 3) & 3) << 8) + (p15 << 4) + ((n & 7) << 1);
}
__device__ __forceinline__ void st_frag1(char* buf, int NK, int pg, int n, int p15, float v) {
  *reinterpret_cast<_Float16*>(buf + fragoff(NK, pg, n, p15)) = (_Float16)v;
}
// bias already folded into acc; cvt then packed-f16 relu (2x v_pk_max_f16)
template <bool RELU>
__device__ __forceinline__ void st_frag4r(char* buf, int NK, int pg, int n, int p15, f32x4 v) {
  h16x2 lo = __builtin_bit_cast(h16x2, __builtin_amdgcn_cvt_pkrtz(v[0], v[1]));
  h16x2 hi = __builtin_bit_cast(h16x2, __builtin_amdgcn_cvt_pkrtz(v[2], v[3]));
  if (RELU) {
    const h16x2 z = {(_Float16)0.f, (_Float16)0.f};
    lo = __builtin_elementwise_max(lo, z);
    hi = __builtin_elementwise_max(hi, z);
  }
  *reinterpret_cast<uint2*>(buf + fragoff(NK, pg, n, p15)) =
      uint2{__builtin_bit_cast(unsigned, lo), __builtin_bit_cast(unsigned, hi)};
}

// ---------- prologue 1: transpose all 3 planes (32,H,W) fp32 -> (H*W,32) fp16 --
__global__ void KPlanes_tr3(const float* __restrict__ yx, const float* __restrict__ xt,
                            const float* __restrict__ yt, uint4* __restrict__ d0,
                            uint4* __restrict__ d1, uint4* __restrict__ d2) {
  const int HW0 = 518400, HW1 = 288000, HW2 = 162000;
  const int NB0 = 2025, NB1 = 1125;
  const int b = blockIdx.x;
  const float* src;
  uint4* dst;
  int HW, s;
  if (b < NB0) {
    src = yx; dst = d0; HW = HW0; s = b * 256 + threadIdx.x;
  } else if (b < NB0 + NB1) {
    src = xt; dst = d1; HW = HW1; s = (b - NB0) * 256 + threadIdx.x;
  } else {
    src = yt; dst = d2; HW = HW2; s = (b - NB0 - NB1) * 256 + threadIdx.x;
  }
  if (s >= HW) return;
#pragma unroll
  for (int g = 0; g < 4; ++g) {
    u16x8 v;
#pragma unroll
    for (int j = 0; j < 8; ++j) {
      const float w = src[(size_t)(g * 8 + j) * HW + s];
      v[j] = __builtin_bit_cast(unsigned short, (_Float16)w);
    }
    dst[(size_t)s * 4 + g] = __builtin_bit_cast(uint4, v);
  }
}

// ---------- prologue 2: pack ALL fp32 weights into fp16 MFMA fragments --------
__global__ void KPlanes_packall(const float* __restrict__ fw1, const float* __restrict__ fw2,
                                const float* __restrict__ w1, const float* __restrict__ w2,
                                const float* __restrict__ w3, const float* __restrict__ w4,
                                uint4* __restrict__ dst) {
  const int F = blockIdx.x * 4 + (threadIdx.x >> 6);
  const int lane = threadIdx.x & 63;
  if (F >= 340) return;
  const float* W;
  int N, K, KS, fbase;
  if (F < 4)        { W = fw1; N = 64;  K = 32;  KS = 1; fbase = 0; }
  else if (F < 12)  { W = fw2; N = 64;  K = 64;  KS = 2; fbase = 4; }
  else if (F < 76)  { W = w1;  N = 256; K = 119; KS = 4; fbase = 12; }
  else if (F < 204) { W = w2;  N = 256; K = 256; KS = 8; fbase = 76; }
  else if (F < 332) { W = w3;  N = 256; K = 256; KS = 8; fbase = 204; }
  else              { W = w4;  N = 3;   K = 256; KS = 8; fbase = 332; }
  const int f = F - fbase;
  const int g = f / KS, ks = f - g * KS;
  const int col = g * 16 + (lane & 15);
  u16x8 v;
#pragma unroll
  for (int j = 0; j < 8; ++j) {
    const int k = ks * 32 + (lane >> 4) * 8 + j;
    const float w = (k < K && col < N) ? W[(size_t)k * N + col] : 0.0f;
    v[j] = __builtin_bit_cast(unsigned short, (_Float16)w);
  }
  dst[(size_t)F * 64 + lane] = __builtin_bit_cast(uint4, v);
}

// ---------- fp16 bilinear sample, 4 channels per thread -----------------------
struct Smp4 {
  uint2 c00, c01, c10, c11;
  float w00, w01, w10, w11;
};
__device__ __forceinline__ Smp4 sample_ld4(const uint2* __restrict__ plt, int Hd, int Wd, float u,
                                           float v, int q) {
  Smp4 s;
  float ix = fminf(fmaxf(u * (float)Wd - 0.5f, 0.f), (float)Wd - 1.f);
  float iy = fminf(fmaxf(v * (float)Hd - 0.5f, 0.f), (float)Hd - 1.f);
  float x0f = floorf(ix), y0f = floorf(iy);
  float wx = ix - x0f, wy = iy - y0f;
  int x0 = (int)x0f, y0 = (int)y0f;
  int x1 = min(x0 + 1, Wd - 1), y1 = min(y0 + 1, Hd - 1);
  s.w00 = (1.f - wx) * (1.f - wy);
  s.w01 = wx * (1.f - wy);
  s.w10 = (1.f - wx) * wy;
  s.w11 = wx * wy;
  const size_t r0 = (size_t)y0 * Wd, r1 = (size_t)y1 * Wd;
  s.c00 = plt[(r0 + x0) * 8 + q];
  s.c01 = plt[(r0 + x1) * 8 + q];
  s.c10 = plt[(r1 + x0) * 8 + q];
  s.c11 = plt[(r1 + x1) * 8 + q];
  return s;
}
__device__ __forceinline__ h16x4 smp_combine4h(const Smp4& s) {
  const h16x4 a = __builtin_bit_cast(h16x4, s.c00);
  const h16x4 b = __builtin_bit_cast(h16x4, s.c01);
  const h16x4 c = __builtin_bit_cast(h16x4, s.c10);
  const h16x4 d = __builtin_bit_cast(h16x4, s.c11);
  const _Float16 w00 = (_Float16)s.w00, w01 = (_Float16)s.w01;
  const _Float16 w10 = (_Float16)s.w10, w11 = (_Float16)s.w11;
  return a * w00 + b * w01 + c * w10 + d * w11;
}

// ---------- ping-pong MFMA layer, bias-in-acc + packed-f16 relu ---------------
template <int KS, int NKOUT, int NT, int MTPW, bool RELU>
__device__ __forceinline__ void layer_fp(const char* in, char* outb, const uint4* __restrict__ Wf,
                                         const float* __restrict__ bg, int gbase, int moff,
                                         int lane) {
  const int l15 = lane & 15, lhi = lane >> 4;
  const char* rb = in + lane * 16 + moff * (KS << 10);
  f32x4 acc[MTPW][NT];
#pragma unroll
  for (int t = 0; t < NT; ++t) {
    const float4 bb = *reinterpret_cast<const float4*>(&bg[(gbase + t) * 16 + lhi * 4]);
#pragma unroll
    for (int m = 0; m < MTPW; ++m) acc[m][t] = f32x4{bb.x, bb.y, bb.z, bb.w};
  }
#pragma unroll
  for (int ks = 0; ks < KS; ++ks) {
    h16x8 wa[NT];
#pragma unroll
    for (int t = 0; t < NT; ++t)
      wa[t] = __builtin_bit_cast(h16x8, Wf[(size_t)((gbase + t) * KS + ks) * 64 + lane]);
#pragma unroll
    for (int m = 0; m < MTPW; ++m) {
      const uint4 u = *reinterpret_cast<const uint4*>(rb + ((m * KS + ks) << 10));
      const h16x8 b = __builtin_bit_cast(h16x8, u);
#pragma unroll
      for (int t = 0; t < NT; ++t)
        acc[m][t] = __builtin_amdgcn_mfma_f32_16x16x32_f16(wa[t], b, acc[m][t], 0, 0, 0);
    }
  }
#pragma unroll
  for (int t = 0; t < NT; ++t) {
    const int ncol = (gbase + t) * 16 + lhi * 4;
#pragma unroll
    for (int m = 0; m < MTPW; ++m)
      st_frag4r<RELU>(outb, NKOUT, moff + m, ncol, l15, acc[m][t]);
  }
}

// ---------- main fused kernel: 64 pts/block, 8 waves, 64 KB LDS, 2 blk/CU -----
__global__ __launch_bounds__(NTHR, 4) void KPlanes_fusedB(
    const float* __restrict__ xyt, const uint2* __restrict__ yx_h, const uint2* __restrict__ xt_h,
    const uint2* __restrict__ yt_h, const uint4* __restrict__ wf1, const float* __restrict__ fb1,
    const uint4* __restrict__ wf2, const float* __restrict__ fb2, const uint4* __restrict__ wf3,
    const float* __restrict__ b1, const uint4* __restrict__ wf4, const float* __restrict__ b2,
    const uint4* __restrict__ wf5, const float* __restrict__ b3, const uint4* __restrict__ wf6,
    const float* __restrict__ b4, const int* __restrict__ fnum_p, float* __restrict__ out) {
  __shared__ char actS[32768];
  __shared__ char actB[32768];
  const int tid = threadIdx.x;
  const int lane = tid & 63;
  const int wid = tid >> 6;
  const float rfn = 1.0f / (float)(*fnum_p);

  // ---- phase 0: gather (8 thr/point, 4 ch each) + pos-enc
  {
    const int p = tid >> 3;
    const int q = tid & 7;
    const int pg = p >> 4, p15 = p & 15;
    const int pgl = blockIdx.x * MT + p;
    const float x = xyt[pgl * 3 + 0];
    const float y = xyt[pgl * 3 + 1];
    const float t = xyt[pgl * 3 + 2] * rfn;
    Smp4 sYX = sample_ld4(yx_h, 540, 960, y, x, q);
    Smp4 sXT = sample_ld4(xt_h, 960, 300, x, t, q);
    Smp4 sYT = sample_ld4(yt_h, 540, 300, y, t, q);
    // pos-enc into NK=4 frags of actS (neurons 64..118), zeros 119..127
    if (q == 4) {
      st_frag1(actS, 4, pg, 64, p15, y);
      float sj, cj;
      sincosf(y, &sj, &cj);
#pragma unroll
      for (int j = 0; j < 10; ++j) {
        st_frag1(actS, 4, pg, 66 + j * 4, p15, sj);
        st_frag1(actS, 4, pg, 68 + j * 4, p15, cj);
        const float ns = 2.f * sj * cj;
        cj = fmaf(-2.f * sj, sj, 1.f);
        sj = ns;
      }
    } else if (q == 5) {
      st_frag1(actS, 4, pg, 65, p15, x);
      float sj, cj;
      sincosf(x, &sj, &cj);
#pragma unroll
      for (int j = 0; j < 10; ++j) {
        st_frag1(actS, 4, pg, 67 + j * 4, p15, sj);
        st_frag1(actS, 4, pg, 69 + j * 4, p15, cj);
        const float ns = 2.f * sj * cj;
        cj = fmaf(-2.f * sj, sj, 1.f);
        sj = ns;
      }
    } else if (q == 6) {
      st_frag1(actS, 4, pg, 106, p15, t);
      float sj, cj;
      sincosf(t, &sj, &cj);
#pragma unroll
      for (int j = 0; j < 6; ++j) {
        st_frag1(actS, 4, pg, 107 + 2 * j, p15, sj);
        st_frag1(actS, 4, pg, 108 + 2 * j, p15, cj);
        const float ns = 2.f * sj * cj;
        cj = fmaf(-2.f * sj, sj, 1.f);
        sj = ns;
      }
    } else if (q == 7) {
      st_frag1(actS, 4, pg, 119, p15, 0.f);
      *reinterpret_cast<uint4*>(actS + fragoff(4, pg, 120, p15)) = uint4{0u, 0u, 0u, 0u};
    }
    const h16x4 fa = smp_combine4h(sYX);
    const h16x4 fb = smp_combine4h(sXT);
    const h16x4 fc = smp_combine4h(sYT);
    const h16x4 prod = fa * fb * fc;
    *reinterpret_cast<uint2*>(actS + 16384 + fragoff(1, pg, q * 4, p15)) =
        __builtin_bit_cast(uint2, prod);
  }
  __syncthreads();
  // L1: feat(32)->h1(64): actS.feat -> actB NK2
  layer_fp<1, 2, 1, 2, true>(actS + 16384, actB, wf1, fb1, wid & 3, (wid >> 2) * 2, lane);
  __syncthreads();
  // L2: h1->h2(64): actB -> actS NK4 frags 0-1 (posenc frags 2-3 untouched)
  layer_fp<2, 4, 1, 2, true>(actB, actS, wf2, fb2, wid & 3, (wid >> 2) * 2, lane);
  __syncthreads();
  // L3: [h2|pe](128)->z1(256): actS NK4 -> actB NK8
  layer_fp<4, 8, 2, 4, true>(actS, actB, wf3, b1, wid * 2, 0, lane);
  __syncthreads();
  // L4: z1->z2(256): actB -> actS NK8
  layer_fp<8, 8, 2, 4, true>(actB, actS, wf4, b2, wid * 2, 0, lane);
  __syncthreads();
  // L5: z2->z3(256): actS -> actB
  layer_fp<8, 8, 2, 4, true>(actS, actB, wf5, b3, wid * 2, 0, lane);
  __syncthreads();
  // L6: z3(256)->3 (pad 16), sigmoid, store. Waves 0..3 own the 4 point-groups.
  if (wid < 4) {
    const int l15 = lane & 15, lhi = lane >> 4;
    const char* rb = actB + lane * 16 + wid * 8192;
    f32x4 acc = {0.f, 0.f, 0.f, 0.f};
#pragma unroll
    for (int ks = 0; ks < 8; ++ks) {
      const h16x8 wa = __builtin_bit_cast(h16x8, wf6[ks * 64 + lane]);
      const h16x8 b = __builtin_bit_cast(h16x8, *reinterpret_cast<const uint4*>(rb + (ks << 10)));
      acc = __builtin_amdgcn_mfma_f32_16x16x32_f16(wa, b, acc, 0, 0, 0);
    }
    if (lhi == 0) {
      const size_t pgl = (size_t)blockIdx.x * MT + wid * 16 + l15;
#pragma unroll
      for (int i = 0; i < 3; ++i) {
        const float v = acc[i] + b4[i];
        out[pgl * 3 + i] = 1.f / (1.f + expf(-v));
      }
    }
  }
}

// ================= fallback (fp32 weights, direct plane sampling) =============
__device__ __forceinline__ int swz(int row, int colbyte) {
  return row * 512 + (colbyte ^ ((row & 31) << 4));
}
__device__ __forceinline__ void st_act(unsigned short* buf, int row, int col, float v) {
  buf[swz(row, col * 2) >> 1] = __builtin_bit_cast(unsigned short, (bf16_t)v);
}
__device__ __forceinline__ bf16x8 ld_frag(const unsigned short* buf, int row, int kbyte) {
  const uint4 u =
      *reinterpret_cast<const uint4*>(reinterpret_cast<const char*>(buf) + swz(row, kbyte));
  return __builtin_bit_cast(bf16x8, u);
}
__device__ __forceinline__ void sample8_f(const float* __restrict__ pl, int Hd, int Wd, float u,
                                          float v, int cgrp, float* o) {
  float ix = fminf(fmaxf(u * (float)Wd - 0.5f, 0.f), (float)Wd - 1.f);
  float iy = fminf(fmaxf(v * (float)Hd - 0.5f, 0.f), (float)Hd - 1.f);
  float x0f = floorf(ix), y0f = floorf(iy);
  float wx = ix - x0f, wy = iy - y0f;
  int x0 = (int)x0f, y0 = (int)y0f;
  int x1 = min(x0 + 1, Wd - 1), y1 = min(y0 + 1, Hd - 1);
  float w00 = (1.f - wx) * (1.f - wy), w01 = wx * (1.f - wy);
  float w10 = (1.f - wx) * wy, w11 = wx * wy;
  const size_t HW = (size_t)Hd * Wd;
#pragma unroll
  for (int i = 0; i < 8; ++i) {
    const float* bc = pl + (size_t)(cgrp + i) * HW;
    float a = bc[(size_t)y0 * Wd + x0], b = bc[(size_t)y0 * Wd + x1];
    float c = bc[(size_t)y1 * Wd + x0], d = bc[(size_t)y1 * Wd + x1];
    o[i] = a * w00 + b * w01 + c * w10 + d * w11;
  }
}

template <int KSTEPS, int NCPW, bool RELU>
__device__ __forceinline__ void mfma_layer_fb(const unsigned short* inb, unsigned short* outb,
                                              const float* __restrict__ Wg,
                                              const float* __restrict__ bg, int N, int Kmax,
                                              int wid, int lane) {
  const int l15 = lane & 15;
  const int lhi = lane >> 4;
#pragma unroll
  for (int t = 0; t < NCPW; ++t) {
    const int nc = wid * NCPW + t;
    const int col = nc * 16 + l15;
    const float bias = bg[col];
    bf16x8 bfrag[KSTEPS];
#pragma unroll
    for (int ks = 0; ks < KSTEPS; ++ks) {
#pragma unroll
      for (int j = 0; j < 8; ++j) {
        const int k = ks * 32 + lhi * 8 + j;
        float wv = (k < Kmax) ? Wg[(size_t)k * N + col] : 0.0f;
        bfrag[ks][j] = (bf16_t)wv;
      }
    }
#pragma unroll
    for (int m = 0; m < 4; ++m) {
      f32x4 acc = {0.f, 0.f, 0.f, 0.f};
#pragma unroll
      for (int ks = 0; ks < KSTEPS; ++ks) {
        bf16x8 a = ld_frag(inb, m * 16 + l15, ks * 64 + lhi * 16);
        acc = __builtin_amdgcn_mfma_f32_16x16x32_bf16(a, bfrag[ks], acc, 0, 0, 0);
      }
      const int r0 = m * 16 + lhi * 4;
#pragma unroll
      for (int i = 0; i < 4; ++i) {
        float v = acc[i] + bias;
        if (RELU) v = fmaxf(v, 0.f);
        st_act(outb, r0 + i, col, v);
      }
    }
  }
}

__global__ __launch_bounds__(256) void KPlanes_fused_fb(
    const float* __restrict__ xyt, const float* __restrict__ yx, const float* __restrict__ xt,
    const float* __restrict__ yt, const float* __restrict__ fw1, const float* __restrict__ fb1,
    const float* __restrict__ fw2, const float* __restrict__ fb2, const float* __restrict__ w1,
    const float* __restrict__ b1, const float* __restrict__ w2, const float* __restrict__ b2,
    const float* __restrict__ w3, const float* __restrict__ b3, const float* __restrict__ w4,
    const float* __restrict__ b4, const int* __restrict__ fnum_p, float* __restrict__ out) {
  __shared__ unsigned short actA[64 * 256];
  __shared__ unsigned short actB[64 * 256];
  const int tid = threadIdx.x;
  const int lane = tid & 63;
  const int wid = tid >> 6;
  const float fnum = (float)(*fnum_p);
  {
    const int p = tid >> 2;
    const int cgrp = (tid & 3) * 8;
    const int pg = blockIdx.x * 64 + p;
    float x = xyt[pg * 3 + 0];
    float y = xyt[pg * 3 + 1];
    float t = xyt[pg * 3 + 2] / fnum;
    float syx[8], sxt[8], syt[8];
    sample8_f(yx, 540, 960, y, x, cgrp, syx);
    sample8_f(xt, 960, 300, x, t, cgrp, sxt);
    sample8_f(yt, 540, 300, y, t, cgrp, syt);
#pragma unroll
    for (int i = 0; i < 8; ++i) st_act(actA, p, cgrp + i, syx[i] * sxt[i] * syt[i]);
  }
  __syncthreads();
  mfma_layer_fb<1, 1, true>(actA, actB, fw1, fb1, 64, 32, wid, lane);
  __syncthreads();
  mfma_layer_fb<2, 1, true>(actB, actA, fw2, fb2, 64, 64, wid, lane);
  if (tid < 64) {
    const int pg = blockIdx.x * 64 + tid;
    float px = xyt[pg * 3 + 0];
    float py = xyt[pg * 3 + 1];
    float pt = xyt[pg * 3 + 2] / fnum;
    st_act(actA, tid, 64, py);
    st_act(actA, tid, 65, px);
    float sc = 1.f;
#pragma unroll
    for (int j = 0; j < 10; ++j) {
      st_act(actA, tid, 66 + j * 4 + 0, sinf(sc * py));
      st_act(actA, tid, 66 + j * 4 + 1, sinf(sc * px));
      st_act(actA, tid, 66 + j * 4 + 2, cosf(sc * py));
      st_act(actA, tid, 66 + j * 4 + 3, cosf(sc * px));
      sc *= 2.f;
    }
    st_act(actA, tid, 106, pt);
    sc = 1.f;
#pragma unroll
    for (int j = 0; j < 6; ++j) {
      st_act(actA, tid, 107 + j * 2, sinf(sc * pt));
      st_act(actA, tid, 108 + j * 2, cosf(sc * pt));
      sc *= 2.f;
    }
#pragma unroll
    for (int c = 119; c < 128; ++c) st_act(actA, tid, c, 0.f);
  }
  __syncthreads();
  mfma_layer_fb<4, 4, true>(actA, actB, w1, b1, 256, 119, wid, lane);
  __syncthreads();
  mfma_layer_fb<8, 4, true>(actB, actA, w2, b2, 256, 256, wid, lane);
  __syncthreads();
  mfma_layer_fb<8, 4, true>(actA, actB, w3, b3, 256, 256, wid, lane);
  __syncthreads();
  {
    const int p = tid >> 2, c = tid & 3;
    if (c < 3) {
      float acc = 0.f;
#pragma unroll
      for (int k0 = 0; k0 < 256; k0 += 8) {
        int b = swz(p, k0 * 2);
        uint4 u = *reinterpret_cast<const uint4*>(reinterpret_cast<const char*>(actB) + b);
        bf16x8 z = __builtin_bit_cast(bf16x8, u);
#pragma unroll
        for (int j = 0; j < 8; ++j) acc += (float)z[j] * w4[(k0 + j) * 3 + c];
      }
      acc += b4[c];
      out[(size_t)(blockIdx.x * 64 + p) * 3 + c] = 1.f / (1.f + expf(-acc));
    }
  }
}

extern "C" void kernel_launch(void* const* d_in, const int* in_sizes, int n_in, void* d_out,
                              int out_size, void* d_ws, size_t ws_size, hipStream_t stream) {
  const float* xyt = (const float*)d_in[0];
  const float* yx = (const float*)d_in[1];
  const float* xt = (const float*)d_in[2];
  const float* yt = (const float*)d_in[3];
  const float* fw1 = (const float*)d_in[4];
  const float* fb1 = (const float*)d_in[5];
  const float* fw2 = (const float*)d_in[6];
  const float* fb2 = (const float*)d_in[7];
  const float* w1 = (const float*)d_in[8];
  const float* b1 = (const float*)d_in[9];
  const float* w2 = (const float*)d_in[10];
  const float* b2 = (const float*)d_in[11];
  const float* w3 = (const float*)d_in[12];
  const float* b3 = (const float*)d_in[13];
  const float* w4 = (const float*)d_in[14];
  const float* b4 = (const float*)d_in[15];
  const int* fnum = (const int*)d_in[16];
  float* out = (float*)d_out;

  const int hw_yx = 540 * 960, hw_xt = 960 * 300, hw_yt = 540 * 300;
  const size_t plane_bytes = ((size_t)hw_yx + hw_xt + hw_yt) * 64;  // fp16, 64B/site
  const size_t wfrag_bytes = (size_t)340 * 64 * sizeof(uint4);
  const size_t need = plane_bytes + wfrag_bytes;

  char* ws = (char*)d_ws;
  uint2* yx_h = (uint2*)ws;
  uint2* xt_h = (uint2*)(ws + (size_t)hw_yx * 64);
  uint2* yt_h = (uint2*)(ws + (size_t)(hw_yx + hw_xt) * 64);
  uint4* wbase = (uint4*)(ws + plane_bytes);
  uint4* wf1 = wbase + 0 * 64;
  uint4* wf2 = wbase + 4 * 64;
  uint4* wf3 = wbase + 12 * 64;
  uint4* wf4 = wbase + 76 * 64;
  uint4* wf5 = wbase + 204 * 64;
  uint4* wf6 = wbase + 332 * 64;

  if (ws_size >= need) {
    const int nb_tr = 2025 + 1125 + 633;
    KPlanes_tr3<<<nb_tr, 256, 0, stream>>>(yx, xt, yt, (uint4*)yx_h, (uint4*)xt_h, (uint4*)yt_h);
    KPlanes_packall<<<85, 256, 0, stream>>>(fw1, fw2, w1, w2, w3, w4, wbase);
    KPlanes_fusedB<<<NBLK, NTHR, 0, stream>>>(xyt, yx_h, xt_h, yt_h, wf1, fb1, wf2, fb2, wf3, b1,
                                              wf4, b2, wf5, b3, wf6, b4, fnum, out);
  } else {
    KPlanes_fused_fb<<<1048576 / 64, 256, 0, stream>>>(xyt, yx, xt, yt, fw1, fb1, fw2, fb2, w1,
                                                       b1, w2, b2, w3, b3, w4, b4, fnum, out);
  }
}

// Round 14
// 456.716 us; speedup vs baseline: 3.9981x; 1.0020x over previous
//
#include <hip/hip_runtime.h>

typedef __bf16 bf16_t;
typedef __bf16 bf16x8 __attribute__((ext_vector_type(8)));
typedef _Float16 h16x2 __attribute__((ext_vector_type(2)));
typedef _Float16 h16x8 __attribute__((ext_vector_type(8)));
typedef unsigned short u16x8 __attribute__((ext_vector_type(8)));
typedef float f32x4 __attribute__((ext_vector_type(4)));

#define MT 64
#define NTHR 512
#define NBLK (1048576 / MT)

// ---------------- fragment-native LDS layout ----------------------------------
// value(point p, neuron n): byte (pg*NK + (n>>5))*1024 + ((n>>3)&3)*256 + (p&15)*16 + (n&7)*2
// B-fragment (pgroup, kstep) = contiguous 1KB at (pg*NK + ks)*1024 + lane*16.
__device__ __forceinline__ int fragoff(int NK, int pg, int n, int p15) {
  return ((pg * NK + (n >> 5)) << 10) + (((n >> 3) & 3) << 8) + (p15 << 4) + ((n & 7) << 1);
}
__device__ __forceinline__ void st_frag1(char* buf, int NK, int pg, int n, int p15, float v) {
  *reinterpret_cast<_Float16*>(buf + fragoff(NK, pg, n, p15)) = (_Float16)v;
}
// bias already folded into acc; cvt then packed-f16 relu (2x v_pk_max_f16)
template <bool RELU>
__device__ __forceinline__ void st_frag4r(char* buf, int NK, int pg, int n, int p15, f32x4 v) {
  h16x2 lo = __builtin_bit_cast(h16x2, __builtin_amdgcn_cvt_pkrtz(v[0], v[1]));
  h16x2 hi = __builtin_bit_cast(h16x2, __builtin_amdgcn_cvt_pkrtz(v[2], v[3]));
  if (RELU) {
    const h16x2 z = {(_Float16)0.f, (_Float16)0.f};
    lo = __builtin_elementwise_max(lo, z);
    hi = __builtin_elementwise_max(hi, z);
  }
  *reinterpret_cast<uint2*>(buf + fragoff(NK, pg, n, p15)) =
      uint2{__builtin_bit_cast(unsigned, lo), __builtin_bit_cast(unsigned, hi)};
}

// ---------- prologue 1: transpose all 3 planes (32,H,W) fp32 -> (H*W,32) fp16 --
__global__ void KPlanes_tr3(const float* __restrict__ yx, const float* __restrict__ xt,
                            const float* __restrict__ yt, uint4* __restrict__ d0,
                            uint4* __restrict__ d1, uint4* __restrict__ d2) {
  const int HW0 = 518400, HW1 = 288000, HW2 = 162000;
  const int NB0 = 2025, NB1 = 1125;
  const int b = blockIdx.x;
  const float* src;
  uint4* dst;
  int HW, s;
  if (b < NB0) {
    src = yx; dst = d0; HW = HW0; s = b * 256 + threadIdx.x;
  } else if (b < NB0 + NB1) {
    src = xt; dst = d1; HW = HW1; s = (b - NB0) * 256 + threadIdx.x;
  } else {
    src = yt; dst = d2; HW = HW2; s = (b - NB0 - NB1) * 256 + threadIdx.x;
  }
  if (s >= HW) return;
#pragma unroll
  for (int g = 0; g < 4; ++g) {
    u16x8 v;
#pragma unroll
    for (int j = 0; j < 8; ++j) {
      const float w = src[(size_t)(g * 8 + j) * HW + s];
      v[j] = __builtin_bit_cast(unsigned short, (_Float16)w);
    }
    dst[(size_t)s * 4 + g] = __builtin_bit_cast(uint4, v);
  }
}

// ---------- prologue 2: pack ALL fp32 weights into fp16 MFMA fragments --------
__global__ void KPlanes_packall(const float* __restrict__ fw1, const float* __restrict__ fw2,
                                const float* __restrict__ w1, const float* __restrict__ w2,
                                const float* __restrict__ w3, const float* __restrict__ w4,
                                uint4* __restrict__ dst) {
  const int F = blockIdx.x * 4 + (threadIdx.x >> 6);
  const int lane = threadIdx.x & 63;
  if (F >= 340) return;
  const float* W;
  int N, K, KS, fbase;
  if (F < 4)        { W = fw1; N = 64;  K = 32;  KS = 1; fbase = 0; }
  else if (F < 12)  { W = fw2; N = 64;  K = 64;  KS = 2; fbase = 4; }
  else if (F < 76)  { W = w1;  N = 256; K = 119; KS = 4; fbase = 12; }
  else if (F < 204) { W = w2;  N = 256; K = 256; KS = 8; fbase = 76; }
  else if (F < 332) { W = w3;  N = 256; K = 256; KS = 8; fbase = 204; }
  else              { W = w4;  N = 3;   K = 256; KS = 8; fbase = 332; }
  const int f = F - fbase;
  const int g = f / KS, ks = f - g * KS;
  const int col = g * 16 + (lane & 15);
  u16x8 v;
#pragma unroll
  for (int j = 0; j < 8; ++j) {
    const int k = ks * 32 + (lane >> 4) * 8 + j;
    const float w = (k < K && col < N) ? W[(size_t)k * N + col] : 0.0f;
    v[j] = __builtin_bit_cast(unsigned short, (_Float16)w);
  }
  dst[(size_t)F * 64 + lane] = __builtin_bit_cast(uint4, v);
}

// ---------- fp16 bilinear sample, 8 channels per thread (uint4 corners) -------
struct Smp8 {
  uint4 c00, c01, c10, c11;
  float w00, w01, w10, w11;
};
__device__ __forceinline__ Smp8 sample_ld8(const uint4* __restrict__ plt, int Hd, int Wd, float u,
                                           float v, int qq) {
  Smp8 s;
  float ix = fminf(fmaxf(u * (float)Wd - 0.5f, 0.f), (float)Wd - 1.f);
  float iy = fminf(fmaxf(v * (float)Hd - 0.5f, 0.f), (float)Hd - 1.f);
  float x0f = floorf(ix), y0f = floorf(iy);
  float wx = ix - x0f, wy = iy - y0f;
  int x0 = (int)x0f, y0 = (int)y0f;
  int x1 = min(x0 + 1, Wd - 1), y1 = min(y0 + 1, Hd - 1);
  s.w00 = (1.f - wx) * (1.f - wy);
  s.w01 = wx * (1.f - wy);
  s.w10 = (1.f - wx) * wy;
  s.w11 = wx * wy;
  const size_t r0 = (size_t)y0 * Wd, r1 = (size_t)y1 * Wd;
  s.c00 = plt[(r0 + x0) * 4 + qq];
  s.c01 = plt[(r0 + x1) * 4 + qq];
  s.c10 = plt[(r1 + x0) * 4 + qq];
  s.c11 = plt[(r1 + x1) * 4 + qq];
  return s;
}
__device__ __forceinline__ h16x8 smp_combine8h(const Smp8& s) {
  const h16x8 a = __builtin_bit_cast(h16x8, s.c00);
  const h16x8 b = __builtin_bit_cast(h16x8, s.c01);
  const h16x8 c = __builtin_bit_cast(h16x8, s.c10);
  const h16x8 d = __builtin_bit_cast(h16x8, s.c11);
  const _Float16 w00 = (_Float16)s.w00, w01 = (_Float16)s.w01;
  const _Float16 w10 = (_Float16)s.w10, w11 = (_Float16)s.w11;
  return a * w00 + b * w01 + c * w10 + d * w11;
}

// ---------- ping-pong MFMA layer, bias-in-acc + packed-f16 relu ---------------
template <int KS, int NKOUT, int NT, int MTPW, bool RELU>
__device__ __forceinline__ void layer_fp(const char* in, char* outb, const uint4* __restrict__ Wf,
                                         const float* __restrict__ bg, int gbase, int moff,
                                         int lane) {
  const int l15 = lane & 15, lhi = lane >> 4;
  const char* rb = in + lane * 16 + moff * (KS << 10);
  f32x4 acc[MTPW][NT];
#pragma unroll
  for (int t = 0; t < NT; ++t) {
    const float4 bb = *reinterpret_cast<const float4*>(&bg[(gbase + t) * 16 + lhi * 4]);
#pragma unroll
    for (int m = 0; m < MTPW; ++m) acc[m][t] = f32x4{bb.x, bb.y, bb.z, bb.w};
  }
#pragma unroll
  for (int ks = 0; ks < KS; ++ks) {
    h16x8 wa[NT];
#pragma unroll
    for (int t = 0; t < NT; ++t)
      wa[t] = __builtin_bit_cast(h16x8, Wf[(size_t)((gbase + t) * KS + ks) * 64 + lane]);
#pragma unroll
    for (int m = 0; m < MTPW; ++m) {
      const uint4 u = *reinterpret_cast<const uint4*>(rb + ((m * KS + ks) << 10));
      const h16x8 b = __builtin_bit_cast(h16x8, u);
#pragma unroll
      for (int t = 0; t < NT; ++t)
        acc[m][t] = __builtin_amdgcn_mfma_f32_16x16x32_f16(wa[t], b, acc[m][t], 0, 0, 0);
    }
  }
#pragma unroll
  for (int t = 0; t < NT; ++t) {
    const int ncol = (gbase + t) * 16 + lhi * 4;
#pragma unroll
    for (int m = 0; m < MTPW; ++m)
      st_frag4r<RELU>(outb, NKOUT, moff + m, ncol, l15, acc[m][t]);
  }
}

// ---------- main fused kernel: 64 pts/block, 8 waves, 64 KB LDS, 2 blk/CU -----
// phase 0: waves 0-3 sample (4 thr/pt, 8 ch, uint4 loads); waves 4-7 pos-enc.
__global__ __launch_bounds__(NTHR, 4) void KPlanes_fusedC(
    const float* __restrict__ xyt, const uint4* __restrict__ yx_h, const uint4* __restrict__ xt_h,
    const uint4* __restrict__ yt_h, const uint4* __restrict__ wf1, const float* __restrict__ fb1,
    const uint4* __restrict__ wf2, const float* __restrict__ fb2, const uint4* __restrict__ wf3,
    const float* __restrict__ b1, const uint4* __restrict__ wf4, const float* __restrict__ b2,
    const uint4* __restrict__ wf5, const float* __restrict__ b3, const uint4* __restrict__ wf6,
    const float* __restrict__ b4, const int* __restrict__ fnum_p, float* __restrict__ out) {
  __shared__ char actS[32768];
  __shared__ char actB[32768];
  const int tid = threadIdx.x;
  const int lane = tid & 63;
  const int wid = tid >> 6;
  const float rfn = 1.0f / (float)(*fnum_p);

  // ---- phase 0
  if (tid < 256) {
    // samplers: 4 threads/point, 8 channels each
    const int p = tid >> 2, qq = tid & 3;
    const int pg = p >> 4, p15 = p & 15;
    const int pgl = blockIdx.x * MT + p;
    const float x = xyt[pgl * 3 + 0];
    const float y = xyt[pgl * 3 + 1];
    const float t = xyt[pgl * 3 + 2] * rfn;
    Smp8 sYX = sample_ld8(yx_h, 540, 960, y, x, qq);
    Smp8 sXT = sample_ld8(xt_h, 960, 300, x, t, qq);
    Smp8 sYT = sample_ld8(yt_h, 540, 300, y, t, qq);
    const h16x8 fa = smp_combine8h(sYX);
    const h16x8 fb = smp_combine8h(sXT);
    const h16x8 fc = smp_combine8h(sYT);
    const h16x8 prod = fa * fb * fc;
    *reinterpret_cast<uint4*>(actS + 16384 + fragoff(1, pg, qq * 8, p15)) =
        __builtin_bit_cast(uint4, prod);
  } else {
    // pos-enc: 4 threads/point (y-chain, x-chain, t-chain, zero-pad)
    const int r = tid - 256;
    const int p = r >> 2, task = r & 3;
    const int pg = p >> 4, p15 = p & 15;
    const int pgl = blockIdx.x * MT + p;
    if (task == 0) {
      const float y = xyt[pgl * 3 + 1];
      st_frag1(actS, 4, pg, 64, p15, y);
      float sj, cj;
      sincosf(y, &sj, &cj);
#pragma unroll
      for (int j = 0; j < 10; ++j) {
        st_frag1(actS, 4, pg, 66 + j * 4, p15, sj);
        st_frag1(actS, 4, pg, 68 + j * 4, p15, cj);
        const float ns = 2.f * sj * cj;
        cj = fmaf(-2.f * sj, sj, 1.f);
        sj = ns;
      }
    } else if (task == 1) {
      const float x = xyt[pgl * 3 + 0];
      st_frag1(actS, 4, pg, 65, p15, x);
      float sj, cj;
      sincosf(x, &sj, &cj);
#pragma unroll
      for (int j = 0; j < 10; ++j) {
        st_frag1(actS, 4, pg, 67 + j * 4, p15, sj);
        st_frag1(actS, 4, pg, 69 + j * 4, p15, cj);
        const float ns = 2.f * sj * cj;
        cj = fmaf(-2.f * sj, sj, 1.f);
        sj = ns;
      }
    } else if (task == 2) {
      const float t = xyt[pgl * 3 + 2] * rfn;
      st_frag1(actS, 4, pg, 106, p15, t);
      float sj, cj;
      sincosf(t, &sj, &cj);
#pragma unroll
      for (int j = 0; j < 6; ++j) {
        st_frag1(actS, 4, pg, 107 + 2 * j, p15, sj);
        st_frag1(actS, 4, pg, 108 + 2 * j, p15, cj);
        const float ns = 2.f * sj * cj;
        cj = fmaf(-2.f * sj, sj, 1.f);
        sj = ns;
      }
    } else {
      st_frag1(actS, 4, pg, 119, p15, 0.f);
      *reinterpret_cast<uint4*>(actS + fragoff(4, pg, 120, p15)) = uint4{0u, 0u, 0u, 0u};
    }
  }
  __syncthreads();
  // L1: feat(32)->h1(64): actS.feat -> actB NK2
  layer_fp<1, 2, 1, 2, true>(actS + 16384, actB, wf1, fb1, wid & 3, (wid >> 2) * 2, lane);
  __syncthreads();
  // L2: h1->h2(64): actB -> actS NK4 frags 0-1 (posenc frags 2-3 untouched)
  layer_fp<2, 4, 1, 2, true>(actB, actS, wf2, fb2, wid & 3, (wid >> 2) * 2, lane);
  __syncthreads();
  // L3: [h2|pe](128)->z1(256): actS NK4 -> actB NK8
  layer_fp<4, 8, 2, 4, true>(actS, actB, wf3, b1, wid * 2, 0, lane);
  __syncthreads();
  // L4: z1->z2(256): actB -> actS NK8
  layer_fp<8, 8, 2, 4, true>(actB, actS, wf4, b2, wid * 2, 0, lane);
  __syncthreads();
  // L5: z2->z3(256): actS -> actB
  layer_fp<8, 8, 2, 4, true>(actS, actB, wf5, b3, wid * 2, 0, lane);
  __syncthreads();
  // L6: z3(256)->3 (pad 16), sigmoid, store. Waves 0..3 own the 4 point-groups.
  if (wid < 4) {
    const int l15 = lane & 15, lhi = lane >> 4;
    const char* rb = actB + lane * 16 + wid * 8192;
    f32x4 acc = {0.f, 0.f, 0.f, 0.f};
#pragma unroll
    for (int ks = 0; ks < 8; ++ks) {
      const h16x8 wa = __builtin_bit_cast(h16x8, wf6[ks * 64 + lane]);
      const h16x8 b = __builtin_bit_cast(h16x8, *reinterpret_cast<const uint4*>(rb + (ks << 10)));
      acc = __builtin_amdgcn_mfma_f32_16x16x32_f16(wa, b, acc, 0, 0, 0);
    }
    if (lhi == 0) {
      const size_t pgl = (size_t)blockIdx.x * MT + wid * 16 + l15;
#pragma unroll
      for (int i = 0; i < 3; ++i) {
        const float v = acc[i] + b4[i];
        out[pgl * 3 + i] = 1.f / (1.f + expf(-v));
      }
    }
  }
}

// ================= fallback (fp32 weights, direct plane sampling) =============
__device__ __forceinline__ int swz(int row, int colbyte) {
  return row * 512 + (colbyte ^ ((row & 31) << 4));
}
__device__ __forceinline__ void st_act(unsigned short* buf, int row, int col, float v) {
  buf[swz(row, col * 2) >> 1] = __builtin_bit_cast(unsigned short, (bf16_t)v);
}
__device__ __forceinline__ bf16x8 ld_frag(const unsigned short* buf, int row, int kbyte) {
  const uint4 u =
      *reinterpret_cast<const uint4*>(reinterpret_cast<const char*>(buf) + swz(row, kbyte));
  return __builtin_bit_cast(bf16x8, u);
}
__device__ __forceinline__ void sample8_f(const float* __restrict__ pl, int Hd, int Wd, float u,
                                          float v, int cgrp, float* o) {
  float ix = fminf(fmaxf(u * (float)Wd - 0.5f, 0.f), (float)Wd - 1.f);
  float iy = fminf(fmaxf(v * (float)Hd - 0.5f, 0.f), (float)Hd - 1.f);
  float x0f = floorf(ix), y0f = floorf(iy);
  float wx = ix - x0f, wy = iy - y0f;
  int x0 = (int)x0f, y0 = (int)y0f;
  int x1 = min(x0 + 1, Wd - 1), y1 = min(y0 + 1, Hd - 1);
  float w00 = (1.f - wx) * (1.f - wy), w01 = wx * (1.f - wy);
  float w10 = (1.f - wx) * wy, w11 = wx * wy;
  const size_t HW = (size_t)Hd * Wd;
#pragma unroll
  for (int i = 0; i < 8; ++i) {
    const float* bc = pl + (size_t)(cgrp + i) * HW;
    float a = bc[(size_t)y0 * Wd + x0], b = bc[(size_t)y0 * Wd + x1];
    float c = bc[(size_t)y1 * Wd + x0], d = bc[(size_t)y1 * Wd + x1];
    o[i] = a * w00 + b * w01 + c * w10 + d * w11;
  }
}

template <int KSTEPS, int NCPW, bool RELU>
__device__ __forceinline__ void mfma_layer_fb(const unsigned short* inb, unsigned short* outb,
                                              const float* __restrict__ Wg,
                                              const float* __restrict__ bg, int N, int Kmax,
                                              int wid, int lane) {
  const int l15 = lane & 15;
  const int lhi = lane >> 4;
#pragma unroll
  for (int t = 0; t < NCPW; ++t) {
    const int nc = wid * NCPW + t;
    const int col = nc * 16 + l15;
    const float bias = bg[col];
    bf16x8 bfrag[KSTEPS];
#pragma unroll
    for (int ks = 0; ks < KSTEPS; ++ks) {
#pragma unroll
      for (int j = 0; j < 8; ++j) {
        const int k = ks * 32 + lhi * 8 + j;
        float wv = (k < Kmax) ? Wg[(size_t)k * N + col] : 0.0f;
        bfrag[ks][j] = (bf16_t)wv;
      }
    }
#pragma unroll
    for (int m = 0; m < 4; ++m) {
      f32x4 acc = {0.f, 0.f, 0.f, 0.f};
#pragma unroll
      for (int ks = 0; ks < KSTEPS; ++ks) {
        bf16x8 a = ld_frag(inb, m * 16 + l15, ks * 64 + lhi * 16);
        acc = __builtin_amdgcn_mfma_f32_16x16x32_bf16(a, bfrag[ks], acc, 0, 0, 0);
      }
      const int r0 = m * 16 + lhi * 4;
#pragma unroll
      for (int i = 0; i < 4; ++i) {
        float v = acc[i] + bias;
        if (RELU) v = fmaxf(v, 0.f);
        st_act(outb, r0 + i, col, v);
      }
    }
  }
}

__global__ __launch_bounds__(256) void KPlanes_fused_fb(
    const float* __restrict__ xyt, const float* __restrict__ yx, const float* __restrict__ xt,
    const float* __restrict__ yt, const float* __restrict__ fw1, const float* __restrict__ fb1,
    const float* __restrict__ fw2, const float* __restrict__ fb2, const float* __restrict__ w1,
    const float* __restrict__ b1, const float* __restrict__ w2, const float* __restrict__ b2,
    const float* __restrict__ w3, const float* __restrict__ b3, const float* __restrict__ w4,
    const float* __restrict__ b4, const int* __restrict__ fnum_p, float* __restrict__ out) {
  __shared__ unsigned short actA[64 * 256];
  __shared__ unsigned short actB[64 * 256];
  const int tid = threadIdx.x;
  const int lane = tid & 63;
  const int wid = tid >> 6;
  const float fnum = (float)(*fnum_p);
  {
    const int p = tid >> 2;
    const int cgrp = (tid & 3) * 8;
    const int pg = blockIdx.x * 64 + p;
    float x = xyt[pg * 3 + 0];
    float y = xyt[pg * 3 + 1];
    float t = xyt[pg * 3 + 2] / fnum;
    float syx[8], sxt[8], syt[8];
    sample8_f(yx, 540, 960, y, x, cgrp, syx);
    sample8_f(xt, 960, 300, x, t, cgrp, sxt);
    sample8_f(yt, 540, 300, y, t, cgrp, syt);
#pragma unroll
    for (int i = 0; i < 8; ++i) st_act(actA, p, cgrp + i, syx[i] * sxt[i] * syt[i]);
  }
  __syncthreads();
  mfma_layer_fb<1, 1, true>(actA, actB, fw1, fb1, 64, 32, wid, lane);
  __syncthreads();
  mfma_layer_fb<2, 1, true>(actB, actA, fw2, fb2, 64, 64, wid, lane);
  if (tid < 64) {
    const int pg = blockIdx.x * 64 + tid;
    float px = xyt[pg * 3 + 0];
    float py = xyt[pg * 3 + 1];
    float pt = xyt[pg * 3 + 2] / fnum;
    st_act(actA, tid, 64, py);
    st_act(actA, tid, 65, px);
    float sc = 1.f;
#pragma unroll
    for (int j = 0; j < 10; ++j) {
      st_act(actA, tid, 66 + j * 4 + 0, sinf(sc * py));
      st_act(actA, tid, 66 + j * 4 + 1, sinf(sc * px));
      st_act(actA, tid, 66 + j * 4 + 2, cosf(sc * py));
      st_act(actA, tid, 66 + j * 4 + 3, cosf(sc * px));
      sc *= 2.f;
    }
    st_act(actA, tid, 106, pt);
    sc = 1.f;
#pragma unroll
    for (int j = 0; j < 6; ++j) {
      st_act(actA, tid, 107 + j * 2, sinf(sc * pt));
      st_act(actA, tid, 108 + j * 2, cosf(sc * pt));
      sc *= 2.f;
    }
#pragma unroll
    for (int c = 119; c < 128; ++c) st_act(actA, tid, c, 0.f);
  }
  __syncthreads();
  mfma_layer_fb<4, 4, true>(actA, actB, w1, b1, 256, 119, wid, lane);
  __syncthreads();
  mfma_layer_fb<8, 4, true>(actB, actA, w2, b2, 256, 256, wid, lane);
  __syncthreads();
  mfma_layer_fb<8, 4, true>(actA, actB, w3, b3, 256, 256, wid, lane);
  __syncthreads();
  {
    const int p = tid >> 2, c = tid & 3;
    if (c < 3) {
      float acc = 0.f;
#pragma unroll
      for (int k0 = 0; k0 < 256; k0 += 8) {
        int b = swz(p, k0 * 2);
        uint4 u = *reinterpret_cast<const uint4*>(reinterpret_cast<const char*>(actB) + b);
        bf16x8 z = __builtin_bit_cast(bf16x8, u);
#pragma unroll
        for (int j = 0; j < 8; ++j) acc += (float)z[j] * w4[(k0 + j) * 3 + c];
      }
      acc += b4[c];
      out[(size_t)(blockIdx.x * 64 + p) * 3 + c] = 1.f / (1.f + expf(-acc));
    }
  }
}

extern "C" void kernel_launch(void* const* d_in, const int* in_sizes, int n_in, void* d_out,
                              int out_size, void* d_ws, size_t ws_size, hipStream_t stream) {
  const float* xyt = (const float*)d_in[0];
  const float* yx = (const float*)d_in[1];
  const float* xt = (const float*)d_in[2];
  const float* yt = (const float*)d_in[3];
  const float* fw1 = (const float*)d_in[4];
  const float* fb1 = (const float*)d_in[5];
  const float* fw2 = (const float*)d_in[6];
  const float* fb2 = (const float*)d_in[7];
  const float* w1 = (const float*)d_in[8];
  const float* b1 = (const float*)d_in[9];
  const float* w2 = (const float*)d_in[10];
  const float* b2 = (const float*)d_in[11];
  const float* w3 = (const float*)d_in[12];
  const float* b3 = (const float*)d_in[13];
  const float* w4 = (const float*)d_in[14];
  const float* b4 = (const float*)d_in[15];
  const int* fnum = (const int*)d_in[16];
  float* out = (float*)d_out;

  const int hw_yx = 540 * 960, hw_xt = 960 * 300, hw_yt = 540 * 300;
  const size_t plane_bytes = ((size_t)hw_yx + hw_xt + hw_yt) * 64;  // fp16, 64B/site
  const size_t wfrag_bytes = (size_t)340 * 64 * sizeof(uint4);
  const size_t need = plane_bytes + wfrag_bytes;

  char* ws = (char*)d_ws;
  uint4* yx_h = (uint4*)ws;
  uint4* xt_h = (uint4*)(ws + (size_t)hw_yx * 64);
  uint4* yt_h = (uint4*)(ws + (size_t)(hw_yx + hw_xt) * 64);
  uint4* wbase = (uint4*)(ws + plane_bytes);
  uint4* wf1 = wbase + 0 * 64;
  uint4* wf2 = wbase + 4 * 64;
  uint4* wf3 = wbase + 12 * 64;
  uint4* wf4 = wbase + 76 * 64;
  uint4* wf5 = wbase + 204 * 64;
  uint4* wf6 = wbase + 332 * 64;

  if (ws_size >= need) {
    const int nb_tr = 2025 + 1125 + 633;
    KPlanes_tr3<<<nb_tr, 256, 0, stream>>>(yx, xt, yt, yx_h, xt_h, yt_h);
    KPlanes_packall<<<85, 256, 0, stream>>>(fw1, fw2, w1, w2, w3, w4, wbase);
    KPlanes_fusedC<<<NBLK, NTHR, 0, stream>>>(xyt, yx_h, xt_h, yt_h, wf1, fb1, wf2, fb2, wf3, b1,
                                              wf4, b2, wf5, b3, wf6, b4, fnum, out);
  } else {
    KPlanes_fused_fb<<<1048576 / 64, 256, 0, stream>>>(xyt, yx, xt, yt, fw1, fb1, fw2, fb2, w1,
                                                       b1, w2, b2, w3, b3, w4, b4, fnum, out);
  }
}